// Round 1
// baseline (1788.546 us; speedup 1.0000x reference)
//
#include <hip/hip_runtime.h>

// Binarized MLP forward (512x784 -> 3x6144 -> 10), dual binary/real paths.
// Precision plan:
//  - layer1 binary (x @ sign(w1)^T): fp64 VALU GEMM, hi/lo fp32 storage (sign-critical)
//  - layer2/3 binary: fp16 MFMA, EXACT (+-1 products, integer fp32 sums < 2^24)
//  - real path: fp16 MFMA (error << 2% thresholds)
//  - all batch-norm stats and normalization in fp64
// ws layout (bytes):
//   xh    @ 0         : 512x832 fp16 (x cast fp16, zero-padded K)   = 851,968
//   z1lo  @ 851968    : 512x6144 fp32 (fp64 GEMM low part)          = 12,582,912
//   sB    @ 13434880  : 512x6144 fp16 sign(Bout_prev)               = 6,291,456
//   rF    @ 19726336  : 512x6144 fp16 Rout_prev                     = 6,291,456
//   stats @ 26017792  : 4 x 6144 fp64 (m_b, rstd_b, m_r, rstd_r)    = 196,608
// total 26,214,400 bytes (25 MiB)

typedef _Float16 f16x8 __attribute__((ext_vector_type(8)));
typedef _Float16 f16x4 __attribute__((ext_vector_type(4)));
typedef float f32x4 __attribute__((ext_vector_type(4)));

#define MFMA16(a, b, c) __builtin_amdgcn_mfma_f32_16x16x32_f16((a), (b), (c), 0, 0, 0)

#define HIDC 6144
#define BATCH 512

// ---------------------------------------------------------------------------
// x (512x784 fp32) -> xh (512x832 fp16, zero-padded cols 784..831)
__global__ __launch_bounds__(256) void k_prep_x(const float* __restrict__ x,
                                                _Float16* __restrict__ xh) {
  int idx = blockIdx.x * 256 + threadIdx.x;  // over 512*208 float4 positions
  if (idx >= 512 * 208) return;
  int row = idx / 208, c4 = idx - row * 208;
  f16x4 h;
  if (c4 < 196) {
    float4 v = *(const float4*)(x + (size_t)row * 784 + c4 * 4);
    h[0] = (_Float16)v.x; h[1] = (_Float16)v.y; h[2] = (_Float16)v.z; h[3] = (_Float16)v.w;
  } else {
    h[0] = (_Float16)0.f; h[1] = (_Float16)0.f; h[2] = (_Float16)0.f; h[3] = (_Float16)0.f;
  }
  *(f16x4*)(xh + (size_t)row * 832 + c4 * 4) = h;
}

// ---------------------------------------------------------------------------
// fp64 GEMM: Z = x(512x784) @ sign(w1)^T(784x6144); hi/lo fp32 output.
// 64x64 tile, 16x16 threads, 4x4 acc per thread, BK=16, 49 K-steps.
__global__ __launch_bounds__(256) void k_gemm64(const float* __restrict__ x,
                                                const float* __restrict__ w1,
                                                float* __restrict__ Zhi,
                                                float* __restrict__ Zlo) {
  __shared__ double xs[64][17];
  __shared__ double wsm[64][17];
  const int t = threadIdx.x;
  const int tx = t & 15, ty = t >> 4;
  const int bn = blockIdx.x, bm = blockIdx.y;
  double acc[4][4] = {};
  for (int kt = 0; kt < 49; ++kt) {
    int k0 = kt * 16;
#pragma unroll
    for (int i = 0; i < 4; ++i) {
      int p = i * 256 + t;
      int r = p >> 4, k = p & 15;
      xs[r][k] = (double)x[(size_t)(bm * 64 + r) * 784 + k0 + k];
      float wv = w1[(size_t)(bn * 64 + r) * 784 + k0 + k];
      wsm[r][k] = wv > 0.f ? 1.0 : (wv < 0.f ? -1.0 : 0.0);
    }
    __syncthreads();
#pragma unroll
    for (int k = 0; k < 16; ++k) {
      double a0 = xs[ty * 4 + 0][k], a1 = xs[ty * 4 + 1][k];
      double a2 = xs[ty * 4 + 2][k], a3 = xs[ty * 4 + 3][k];
      double b0 = wsm[tx * 4 + 0][k], b1 = wsm[tx * 4 + 1][k];
      double b2 = wsm[tx * 4 + 2][k], b3 = wsm[tx * 4 + 3][k];
      acc[0][0] += a0 * b0; acc[0][1] += a0 * b1; acc[0][2] += a0 * b2; acc[0][3] += a0 * b3;
      acc[1][0] += a1 * b0; acc[1][1] += a1 * b1; acc[1][2] += a1 * b2; acc[1][3] += a1 * b3;
      acc[2][0] += a2 * b0; acc[2][1] += a2 * b1; acc[2][2] += a2 * b2; acc[2][3] += a2 * b3;
      acc[3][0] += a3 * b0; acc[3][1] += a3 * b1; acc[3][2] += a3 * b2; acc[3][3] += a3 * b3;
    }
    __syncthreads();
  }
#pragma unroll
  for (int i = 0; i < 4; ++i)
#pragma unroll
    for (int j = 0; j < 4; ++j) {
      double v = acc[i][j];
      float h = (float)v;
      float l = (float)(v - (double)h);
      size_t o = (size_t)(bm * 64 + ty * 4 + i) * HIDC + bn * 64 + tx * 4 + j;
      Zhi[o] = h;
      Zlo[o] = l;
    }
}

// ---------------------------------------------------------------------------
// Fused dual-path fp16 MFMA GEMM. BM=64, BN=128, BK=64, 4 waves.
// MODE 0 (layer1 real): Zr = A0 @ fp16(W)^T           (A1, Zb unused)
// MODE 1 (layer2/3):    Zb = A0 @ sign(W)^T ; Zr = A1 @ fp16(W)^T
// LDS 48KB: A0@0(8K) A1@8192(8K) B0(sign)@16384(16K) B1(val)@32768(16K)
// XOR swizzle: byte ^= (row&7)<<4 (bank-conflict-free ds_read_b128).
template <int MODE>
__global__ __launch_bounds__(256) void k_gemm(const _Float16* __restrict__ A0,
                                              const _Float16* __restrict__ A1,
                                              const float* __restrict__ W,
                                              float* __restrict__ Zb,
                                              float* __restrict__ Zr,
                                              int KA, int KW, int ksteps) {
  __shared__ __align__(16) char smem[49152];
  const int t = threadIdx.x;
  const int lane = t & 63, wn = t >> 6;
  const int bn = blockIdx.x, bm = blockIdx.y;
  f32x4 accB[4][2];
  f32x4 accR[4][2];
#pragma unroll
  for (int mf = 0; mf < 4; ++mf)
#pragma unroll
    for (int nf = 0; nf < 2; ++nf) {
      accB[mf][nf] = (f32x4){0.f, 0.f, 0.f, 0.f};
      accR[mf][nf] = (f32x4){0.f, 0.f, 0.f, 0.f};
    }

  for (int kt = 0; kt < ksteps; ++kt) {
    const int k0 = kt * 64;
    // ---- stage A tiles (64 rows x 64 k, fp16 source) ----
#pragma unroll
    for (int i = 0; i < 2; ++i) {
      int p = i * 256 + t;
      int r = p >> 3, k8 = p & 7;
      size_t gi = (size_t)(bm * 64 + r) * KA + k0 + k8 * 8;
      int bo = (r * 128 + k8 * 16) ^ ((r & 7) << 4);
      *(f16x8*)(smem + bo) = *(const f16x8*)(A0 + gi);
      if constexpr (MODE == 1) *(f16x8*)(smem + 8192 + bo) = *(const f16x8*)(A1 + gi);
    }
    // ---- stage B tiles (128 rows x 64 k from fp32 W -> sign fp16 + val fp16) ----
#pragma unroll
    for (int i = 0; i < 8; ++i) {
      int p = i * 256 + t;
      int r = p >> 4, c4 = p & 15;
      float4 wv = {0.f, 0.f, 0.f, 0.f};
      if (k0 + c4 * 4 < KW)
        wv = *(const float4*)(W + (size_t)(bn * 128 + r) * KW + k0 + c4 * 4);
      float arr[4] = {wv.x, wv.y, wv.z, wv.w};
      f16x4 hv, hs;
#pragma unroll
      for (int e = 0; e < 4; ++e) {
        hv[e] = (_Float16)arr[e];
        hs[e] = arr[e] > 0.f ? (_Float16)1.0f : (arr[e] < 0.f ? (_Float16)(-1.0f) : (_Float16)0.0f);
      }
      int bo = (r * 128 + c4 * 8) ^ ((r & 7) << 4);
      if constexpr (MODE == 1) *(f16x4*)(smem + 16384 + bo) = hs;
      *(f16x4*)(smem + 32768 + bo) = hv;
    }
    __syncthreads();
    // ---- MFMA ----
#pragma unroll
    for (int kk = 0; kk < 2; ++kk) {
      f16x8 a0[4], a1[4], b0[2], b1[2];
#pragma unroll
      for (int mf = 0; mf < 4; ++mf) {
        int r = mf * 16 + (lane & 15);
        int bo = (r * 128 + kk * 64 + (lane >> 4) * 16) ^ ((r & 7) << 4);
        a0[mf] = *(const f16x8*)(smem + bo);
        if constexpr (MODE == 1) a1[mf] = *(const f16x8*)(smem + 8192 + bo);
      }
#pragma unroll
      for (int nf = 0; nf < 2; ++nf) {
        int r = wn * 32 + nf * 16 + (lane & 15);
        int bo = (r * 128 + kk * 64 + (lane >> 4) * 16) ^ ((r & 7) << 4);
        if constexpr (MODE == 1) b0[nf] = *(const f16x8*)(smem + 16384 + bo);
        b1[nf] = *(const f16x8*)(smem + 32768 + bo);
      }
#pragma unroll
      for (int mf = 0; mf < 4; ++mf)
#pragma unroll
        for (int nf = 0; nf < 2; ++nf) {
          if constexpr (MODE == 1) {
            accB[mf][nf] = MFMA16(a0[mf], b0[nf], accB[mf][nf]);
            accR[mf][nf] = MFMA16(a1[mf], b1[nf], accR[mf][nf]);
          } else {
            accR[mf][nf] = MFMA16(a0[mf], b1[nf], accR[mf][nf]);
          }
        }
    }
    __syncthreads();
  }
  // ---- epilogue: D layout col=lane&15, row=(lane>>4)*4+reg ----
#pragma unroll
  for (int mf = 0; mf < 4; ++mf)
#pragma unroll
    for (int nf = 0; nf < 2; ++nf) {
      int col = bn * 128 + wn * 32 + nf * 16 + (lane & 15);
      int row0 = bm * 64 + mf * 16 + ((lane >> 4) << 2);
#pragma unroll
      for (int rr = 0; rr < 4; ++rr) {
        size_t o = (size_t)(row0 + rr) * HIDC + col;
        if constexpr (MODE == 1) Zb[o] = accB[mf][nf][rr];
        Zr[o] = accR[mf][nf][rr];
      }
    }
}

// ---------------------------------------------------------------------------
// Per-column (6144) mean & rstd over 512 rows, fp64. Optional hi/lo input and
// optional dropout (mask>=0.5 ? 2*(z+b3) : 0) applied before stats.
__global__ __launch_bounds__(256) void k_stats(const float* __restrict__ Z,
                                               const float* __restrict__ Zlo,
                                               const float* __restrict__ msk,
                                               const float* __restrict__ bias,
                                               int dodrop,
                                               double* __restrict__ m_out,
                                               double* __restrict__ r_out) {
  __shared__ double sm[4][64];
  __shared__ double sq[4][64];
  const int li = threadIdx.x & 63, rg = threadIdx.x >> 6;
  const int c = blockIdx.x * 64 + li;
  const double bb = dodrop ? (double)bias[c] : 0.0;
  double s = 0.0, s2 = 0.0;
  for (int r = rg; r < BATCH; r += 4) {
    size_t i = (size_t)r * HIDC + c;
    double v = (double)Z[i];
    if (Zlo) v += (double)Zlo[i];
    if (dodrop) v = (msk[i] >= 0.5f) ? 2.0 * (v + bb) : 0.0;
    s += v;
    s2 += v * v;
  }
  sm[rg][li] = s;
  sq[rg][li] = s2;
  __syncthreads();
  if (rg == 0) {
    double S = sm[0][li] + sm[1][li] + sm[2][li] + sm[3][li];
    double S2 = sq[0][li] + sq[1][li] + sq[2][li] + sq[3][li];
    double m = S / 512.0;
    double var = S2 / 512.0 - m * m;
    m_out[c] = m;
    r_out[c] = 1.0 / sqrt(var + 1e-5);
  }
}

// ---------------------------------------------------------------------------
// In-place BN (+optional dropout first) + hardtanh, fp64 math.
// auxmode: 0 -> write sign(out) fp16 to aux; 1 -> write fp16(out); 2 -> none.
__global__ __launch_bounds__(256) void k_bn(float* __restrict__ Z,
                                            const float* __restrict__ Zlo,
                                            const double* __restrict__ m_arr,
                                            const double* __restrict__ r_arr,
                                            const float* __restrict__ g,
                                            const float* __restrict__ be,
                                            _Float16* __restrict__ aux, int auxmode,
                                            const float* __restrict__ msk,
                                            const float* __restrict__ bias, int dodrop) {
  int idx = blockIdx.x * 256 + threadIdx.x;  // 512*1536 float4 positions
  int row = idx / 1536;
  int c4 = (idx - row * 1536) * 4;
  size_t base = (size_t)row * HIDC + c4;
  float4 z = *(const float4*)(Z + base);
  float zz[4] = {z.x, z.y, z.z, z.w};
  float zl[4] = {0.f, 0.f, 0.f, 0.f};
  if (Zlo) {
    float4 t4 = *(const float4*)(Zlo + base);
    zl[0] = t4.x; zl[1] = t4.y; zl[2] = t4.z; zl[3] = t4.w;
  }
  float mk[4] = {1.f, 1.f, 1.f, 1.f};
  if (dodrop) {
    float4 t4 = *(const float4*)(msk + base);
    mk[0] = t4.x; mk[1] = t4.y; mk[2] = t4.z; mk[3] = t4.w;
  }
  float o[4];
  f16x4 a4;
#pragma unroll
  for (int e = 0; e < 4; ++e) {
    int c = c4 + e;
    double v = (double)zz[e] + (double)zl[e];
    if (dodrop) v = (mk[e] >= 0.5f) ? 2.0 * (v + (double)bias[c]) : 0.0;
    double bnv = (double)g[c] * ((v - m_arr[c]) * r_arr[c]) + (double)be[c];
    bnv = bnv > 1.0 ? 1.0 : (bnv < -1.0 ? -1.0 : bnv);
    o[e] = (float)bnv;
    if (auxmode == 0)
      a4[e] = bnv > 0.0 ? (_Float16)1.0f : (bnv < 0.0 ? (_Float16)(-1.0f) : (_Float16)0.0f);
    else
      a4[e] = (_Float16)o[e];
  }
  float4 ov = {o[0], o[1], o[2], o[3]};
  *(float4*)(Z + base) = ov;
  if (auxmode < 2) *(f16x4*)(aux + base) = a4;
}

// ---------------------------------------------------------------------------
// Head: out = Bout3 @ w4^T + b4 (512x10, K=6144) + log_softmax, one block/row.
__global__ __launch_bounds__(256) void k_head(const float* __restrict__ B3,
                                              const float* __restrict__ w4,
                                              const float* __restrict__ b4,
                                              float* __restrict__ out,
                                              float* __restrict__ logp) {
  const int row = blockIdx.x, t = threadIdx.x;
  float acc[10];
#pragma unroll
  for (int j = 0; j < 10; ++j) acc[j] = 0.f;
  const float* a = B3 + (size_t)row * HIDC;
  for (int k4 = t; k4 < 1536; k4 += 256) {
    float4 av = *(const float4*)(a + k4 * 4);
#pragma unroll
    for (int j = 0; j < 10; ++j) {
      float4 wv = *(const float4*)(w4 + (size_t)j * HIDC + k4 * 4);
      acc[j] += av.x * wv.x + av.y * wv.y + av.z * wv.z + av.w * wv.w;
    }
  }
#pragma unroll
  for (int j = 0; j < 10; ++j)
    for (int off = 32; off; off >>= 1) acc[j] += __shfl_down(acc[j], off);
  __shared__ float sred[4][10];
  int wid = t >> 6, ln = t & 63;
  if (ln == 0)
#pragma unroll
    for (int j = 0; j < 10; ++j) sred[wid][j] = acc[j];
  __syncthreads();
  if (t == 0) {
    double o[10];
    double mx = -1e300;
#pragma unroll
    for (int j = 0; j < 10; ++j) {
      o[j] = (double)sred[0][j] + sred[1][j] + sred[2][j] + sred[3][j] + (double)b4[j];
      mx = o[j] > mx ? o[j] : mx;
    }
    double s = 0.0;
#pragma unroll
    for (int j = 0; j < 10; ++j) s += exp(o[j] - mx);
    double l = log(s) + mx;
#pragma unroll
    for (int j = 0; j < 10; ++j) {
      out[row * 10 + j] = (float)o[j];
      logp[row * 10 + j] = (float)(o[j] - l);
    }
  }
}

// ---------------------------------------------------------------------------
extern "C" void kernel_launch(void* const* d_in, const int* in_sizes, int n_in,
                              void* d_out, int out_size, void* d_ws, size_t ws_size,
                              hipStream_t stream) {
  const float* x   = (const float*)d_in[0];
  const float* mkb = (const float*)d_in[1];
  const float* mkr = (const float*)d_in[2];
  const float* w1  = (const float*)d_in[3];
  const float* w2  = (const float*)d_in[5];
  const float* w3  = (const float*)d_in[7];
  const float* b3  = (const float*)d_in[8];
  const float* w4  = (const float*)d_in[9];
  const float* b4  = (const float*)d_in[10];
  const float* g1  = (const float*)d_in[11]; const float* be1 = (const float*)d_in[12];
  const float* g2  = (const float*)d_in[13]; const float* be2 = (const float*)d_in[14];
  const float* g3  = (const float*)d_in[15]; const float* be3 = (const float*)d_in[16];

  float* outp = (float*)d_out;
  float* logp = outp;
  float* outo = outp + 5120;
  float* B1 = outp + 10240;
  float* R1 = outp + 3155968;
  float* B2 = outp + 6301696;
  float* R2 = outp + 9447424;
  float* B3 = outp + 12593152;
  float* R3 = outp + 15738880;

  char* ws = (char*)d_ws;
  _Float16* xh  = (_Float16*)ws;
  float* z1lo   = (float*)(ws + 851968);
  _Float16* sB  = (_Float16*)(ws + 13434880);
  _Float16* rF  = (_Float16*)(ws + 19726336);
  double* stats = (double*)(ws + 26017792);
  double* m_b = stats, * r_b = stats + 6144, * m_r = stats + 12288, * r_r = stats + 18432;

  // ---- layer 1 ----
  k_prep_x<<<416, 256, 0, stream>>>(x, xh);
  k_gemm64<<<dim3(96, 8), 256, 0, stream>>>(x, w1, B1, z1lo);
  k_gemm<0><<<dim3(48, 8), 256, 0, stream>>>(xh, nullptr, w1, nullptr, R1, 832, 784, 13);
  k_stats<<<96, 256, 0, stream>>>(B1, z1lo, nullptr, nullptr, 0, m_b, r_b);
  k_stats<<<96, 256, 0, stream>>>(R1, nullptr, nullptr, nullptr, 0, m_r, r_r);
  k_bn<<<3072, 256, 0, stream>>>(B1, z1lo, m_b, r_b, g1, be1, sB, 0, nullptr, nullptr, 0);
  k_bn<<<3072, 256, 0, stream>>>(R1, nullptr, m_r, r_r, g1, be1, rF, 1, nullptr, nullptr, 0);
  // ---- layer 2 ----
  k_gemm<1><<<dim3(48, 8), 256, 0, stream>>>(sB, rF, w2, B2, R2, 6144, 6144, 96);
  k_stats<<<96, 256, 0, stream>>>(B2, nullptr, nullptr, nullptr, 0, m_b, r_b);
  k_stats<<<96, 256, 0, stream>>>(R2, nullptr, nullptr, nullptr, 0, m_r, r_r);
  k_bn<<<3072, 256, 0, stream>>>(B2, nullptr, m_b, r_b, g2, be2, sB, 0, nullptr, nullptr, 0);
  k_bn<<<3072, 256, 0, stream>>>(R2, nullptr, m_r, r_r, g2, be2, rF, 1, nullptr, nullptr, 0);
  // ---- layer 3 (+dropout before BN) ----
  k_gemm<1><<<dim3(48, 8), 256, 0, stream>>>(sB, rF, w3, B3, R3, 6144, 6144, 96);
  k_stats<<<96, 256, 0, stream>>>(B3, nullptr, mkb, b3, 1, m_b, r_b);
  k_stats<<<96, 256, 0, stream>>>(R3, nullptr, mkr, b3, 1, m_r, r_r);
  k_bn<<<3072, 256, 0, stream>>>(B3, nullptr, m_b, r_b, g3, be3, nullptr, 2, mkb, b3, 1);
  k_bn<<<3072, 256, 0, stream>>>(R3, nullptr, m_r, r_r, g3, be3, nullptr, 2, mkr, b3, 1);
  // ---- head ----
  k_head<<<512, 256, 0, stream>>>(B3, w4, b4, outo, logp);
}

// Round 2
// 849.965 us; speedup vs baseline: 2.1043x; 2.1043x over previous
//
#include <hip/hip_runtime.h>

// Binarized MLP forward (512x784 -> 3x6144 -> 10), dual binary/real paths.
// Round 2: pre-convert W to fp16 val+sign once per layer; m97-style 128x128x64
// single-path MFMA GEMM with global_load_lds and split-K=2 (768 blocks = 3/CU);
// two-stage column stats. Fallback to round-1 path if ws_size too small.
//
// Precision plan (unchanged, validated round 1):
//  - layer1 binary (x @ sign(w1)^T): fp64 VALU GEMM, hi/lo fp32 storage
//  - layer2/3 binary: fp16 MFMA, EXACT (+-1 products, integer fp32 sums < 2^24;
//    split-K partials are integers -> deterministic exact reduction)
//  - real path: fp16 MFMA (error ~1e-3 << 2% thresholds)
//  - all batch-norm stats and normalization in fp64

typedef _Float16 f16x8 __attribute__((ext_vector_type(8)));
typedef _Float16 f16x4 __attribute__((ext_vector_type(4)));
typedef float f32x4 __attribute__((ext_vector_type(4)));

#define MFMA16(a, b, c) __builtin_amdgcn_mfma_f32_16x16x32_f16((a), (b), (c), 0, 0, 0)

#define HIDC 6144
#define BATCH 512

// ---- workspace layout (bytes) ----
#define OFF_XH    0ull          // 512x832 fp16                    851,968
#define OFF_Z1LO  851968ull     // 512x6144 fp32                12,582,912
#define OFF_SB    13434880ull   // 512x6144 fp16                 6,291,456
#define OFF_RF    19726336ull   // 512x6144 fp16                 6,291,456
#define OFF_STATS 26017792ull   // 4x6144 fp64                     196,608
#define OFF_PPART 26214400ull   // 2x8x2x6144 fp64               1,572,864
#define OFF_ZPB   27787264ull   // 512x6144 fp32 (splitK bin)   12,582,912
#define OFF_ZPR   40370176ull   // 512x6144 fp32 (splitK real)  12,582,912
#define OFF_W1V   52953088ull   // 6144x832 fp16                10,223,616
#define OFF_WV    63176704ull   // 6144x6144 fp16               75,497,472
#define OFF_WS2   138674176ull  // 6144x6144 fp16               75,497,472
#define WS_NEED   214171648ull

// ---------------------------------------------------------------------------
__device__ __forceinline__ void load_lds16(const void* g, char* lds) {
  __builtin_amdgcn_global_load_lds((const __attribute__((address_space(1))) void*)g,
                                   (__attribute__((address_space(3))) void*)lds, 16, 0, 0);
}

// ---------------------------------------------------------------------------
// x (512x784 fp32) -> xh (512x832 fp16, zero-padded cols 784..831)
__global__ __launch_bounds__(256) void k_prep_x(const float* __restrict__ x,
                                                _Float16* __restrict__ xh) {
  int idx = blockIdx.x * 256 + threadIdx.x;  // over 512*208 float4 positions
  if (idx >= 512 * 208) return;
  int row = idx / 208, c4 = idx - row * 208;
  f16x4 h;
  if (c4 < 196) {
    float4 v = *(const float4*)(x + (size_t)row * 784 + c4 * 4);
    h[0] = (_Float16)v.x; h[1] = (_Float16)v.y; h[2] = (_Float16)v.z; h[3] = (_Float16)v.w;
  } else {
    h[0] = (_Float16)0.f; h[1] = (_Float16)0.f; h[2] = (_Float16)0.f; h[3] = (_Float16)0.f;
  }
  *(f16x4*)(xh + (size_t)row * 832 + c4 * 4) = h;
}

// ---------------------------------------------------------------------------
// w1 (6144x784 fp32) -> W1v (6144x832 fp16, zero-padded)
__global__ __launch_bounds__(256) void k_conv_w1(const float* __restrict__ w,
                                                 _Float16* __restrict__ wv) {
  int idx = blockIdx.x * 256 + threadIdx.x;  // 6144*104 f16x8 groups
  if (idx >= 6144 * 104) return;
  int r = idx / 104, c8 = idx - r * 104;
  f16x8 hv;
  if (c8 < 98) {
    const float* s = w + (size_t)r * 784 + c8 * 8;
    float4 v0 = *(const float4*)s;
    float4 v1 = *(const float4*)(s + 4);
    float a[8] = {v0.x, v0.y, v0.z, v0.w, v1.x, v1.y, v1.z, v1.w};
#pragma unroll
    for (int e = 0; e < 8; ++e) hv[e] = (_Float16)a[e];
  } else {
#pragma unroll
    for (int e = 0; e < 8; ++e) hv[e] = (_Float16)0.f;
  }
  *(f16x8*)(wv + (size_t)r * 832 + c8 * 8) = hv;
}

// ---------------------------------------------------------------------------
// w (6144x6144 fp32) -> Wv (fp16 value), Wsg (fp16 sign)
__global__ __launch_bounds__(256) void k_conv_w23(const float* __restrict__ w,
                                                  _Float16* __restrict__ wv,
                                                  _Float16* __restrict__ wsg) {
  int idx = blockIdx.x * 256 + threadIdx.x;  // 6144*768 f16x8 groups
  size_t o8 = (size_t)idx * 8;
  const float* s = w + o8;
  float4 v0 = *(const float4*)s;
  float4 v1 = *(const float4*)(s + 4);
  float a[8] = {v0.x, v0.y, v0.z, v0.w, v1.x, v1.y, v1.z, v1.w};
  f16x8 hv, hs;
#pragma unroll
  for (int e = 0; e < 8; ++e) {
    hv[e] = (_Float16)a[e];
    hs[e] = a[e] > 0.f ? (_Float16)1.0f : (a[e] < 0.f ? (_Float16)(-1.0f) : (_Float16)0.0f);
  }
  *(f16x8*)(wv + o8) = hv;
  *(f16x8*)(wsg + o8) = hs;
}

// ---------------------------------------------------------------------------
// fp64 GEMM: Z = x(512x784) @ sign(w1)^T(784x6144); hi/lo fp32 output.
__global__ __launch_bounds__(256) void k_gemm64(const float* __restrict__ x,
                                                const float* __restrict__ w1,
                                                float* __restrict__ Zhi,
                                                float* __restrict__ Zlo) {
  __shared__ double xs[64][17];
  __shared__ double wsm[64][17];
  const int t = threadIdx.x;
  const int tx = t & 15, ty = t >> 4;
  const int bn = blockIdx.x, bm = blockIdx.y;
  double acc[4][4] = {};
  for (int kt = 0; kt < 49; ++kt) {
    int k0 = kt * 16;
#pragma unroll
    for (int i = 0; i < 4; ++i) {
      int p = i * 256 + t;
      int r = p >> 4, k = p & 15;
      xs[r][k] = (double)x[(size_t)(bm * 64 + r) * 784 + k0 + k];
      float wv = w1[(size_t)(bn * 64 + r) * 784 + k0 + k];
      wsm[r][k] = wv > 0.f ? 1.0 : (wv < 0.f ? -1.0 : 0.0);
    }
    __syncthreads();
#pragma unroll
    for (int k = 0; k < 16; ++k) {
      double a0 = xs[ty * 4 + 0][k], a1 = xs[ty * 4 + 1][k];
      double a2 = xs[ty * 4 + 2][k], a3 = xs[ty * 4 + 3][k];
      double b0 = wsm[tx * 4 + 0][k], b1 = wsm[tx * 4 + 1][k];
      double b2 = wsm[tx * 4 + 2][k], b3 = wsm[tx * 4 + 3][k];
      acc[0][0] += a0 * b0; acc[0][1] += a0 * b1; acc[0][2] += a0 * b2; acc[0][3] += a0 * b3;
      acc[1][0] += a1 * b0; acc[1][1] += a1 * b1; acc[1][2] += a1 * b2; acc[1][3] += a1 * b3;
      acc[2][0] += a2 * b0; acc[2][1] += a2 * b1; acc[2][2] += a2 * b2; acc[2][3] += a2 * b3;
      acc[3][0] += a3 * b0; acc[3][1] += a3 * b1; acc[3][2] += a3 * b2; acc[3][3] += a3 * b3;
    }
    __syncthreads();
  }
#pragma unroll
  for (int i = 0; i < 4; ++i)
#pragma unroll
    for (int j = 0; j < 4; ++j) {
      double v = acc[i][j];
      float h = (float)v;
      float l = (float)(v - (double)h);
      size_t o = (size_t)(bm * 64 + ty * 4 + i) * HIDC + bn * 64 + tx * 4 + j;
      Zhi[o] = h;
      Zlo[o] = l;
    }
}

// ---------------------------------------------------------------------------
// m97-style fp16 GEMM: C[M x N] = A[M x K] @ B[N x K]^T, BM=BN=128, BK=64,
// 4 waves (2x2), global_load_lds staging, linear LDS, 2-barrier K-loop.
// grid (N/128, M/128, njobs); blockIdx.z picks the job (path / K-half).
struct GemmJob {
  const _Float16* A;
  const _Float16* B;
  float* C;
  int K;
  int kstart;
  int ksteps;
};
struct Gemm4 { GemmJob j[4]; };

__global__ __launch_bounds__(256) void k_gemm16(Gemm4 P) {
  __shared__ __align__(16) char smem[32768];  // A @0 (16K), B @16384 (16K)
  GemmJob J = P.j[0];
  if (blockIdx.z == 1) J = P.j[1];
  if (blockIdx.z == 2) J = P.j[2];
  if (blockIdx.z == 3) J = P.j[3];
  const int t = threadIdx.x;
  const int lane = t & 63, wid = t >> 6;
  const int wm = wid >> 1, wn = wid & 1;
  const int bn = blockIdx.x, bm = blockIdx.y;
  const size_t K = (size_t)J.K;

  f32x4 acc[4][4];
#pragma unroll
  for (int mf = 0; mf < 4; ++mf)
#pragma unroll
    for (int nf = 0; nf < 4; ++nf) acc[mf][nf] = (f32x4){0.f, 0.f, 0.f, 0.f};

  // per-thread staging coords: p = i*256+t ; row = p>>3 ; c16 = p&7
  for (int kt = 0; kt < J.ksteps; ++kt) {
    const int k0 = J.kstart + kt * 64;
#pragma unroll
    for (int i = 0; i < 4; ++i) {
      int p = i * 256 + t;
      int r = p >> 3, c16 = p & 7;
      load_lds16(J.A + (size_t)(bm * 128 + r) * K + k0 + c16 * 8, smem + p * 16);
    }
#pragma unroll
    for (int i = 0; i < 4; ++i) {
      int p = i * 256 + t;
      int r = p >> 3, c16 = p & 7;
      load_lds16(J.B + (size_t)(bn * 128 + r) * K + k0 + c16 * 8, smem + 16384 + p * 16);
    }
    __syncthreads();
#pragma unroll
    for (int kk = 0; kk < 2; ++kk) {
      f16x8 av[4], bv[4];
#pragma unroll
      for (int mf = 0; mf < 4; ++mf) {
        int r = wm * 64 + mf * 16 + (lane & 15);
        av[mf] = *(const f16x8*)(smem + r * 128 + kk * 64 + (lane >> 4) * 16);
      }
#pragma unroll
      for (int nf = 0; nf < 4; ++nf) {
        int r = wn * 64 + nf * 16 + (lane & 15);
        bv[nf] = *(const f16x8*)(smem + 16384 + r * 128 + kk * 64 + (lane >> 4) * 16);
      }
#pragma unroll
      for (int mf = 0; mf < 4; ++mf)
#pragma unroll
        for (int nf = 0; nf < 4; ++nf) acc[mf][nf] = MFMA16(av[mf], bv[nf], acc[mf][nf]);
    }
    __syncthreads();
  }
  // epilogue: D layout col=lane&15, row=(lane>>4)*4+reg
#pragma unroll
  for (int mf = 0; mf < 4; ++mf)
#pragma unroll
    for (int nf = 0; nf < 4; ++nf) {
      int col = bn * 128 + wn * 64 + nf * 16 + (lane & 15);
      int row0 = bm * 128 + wm * 64 + mf * 16 + ((lane >> 4) << 2);
#pragma unroll
      for (int rr = 0; rr < 4; ++rr) {
        J.C[(size_t)(row0 + rr) * HIDC + col] = acc[mf][nf][rr];
      }
    }
}

// ---------------------------------------------------------------------------
// Two-stage per-column stats (mean, rstd over 512 rows), fp64.
struct StJob { const float* Z; const float* Zpart; const float* msk; };
struct St2 { StJob j[2]; const float* bias; int dodrop; double* ppart; };

__global__ __launch_bounds__(256) void k_stats_part(St2 P) {
  __shared__ double sm[4][64];
  __shared__ double sq[4][64];
  const int z = blockIdx.z;
  StJob J = z ? P.j[1] : P.j[0];
  const int li = threadIdx.x & 63, rg = threadIdx.x >> 6;
  const int col = blockIdx.x * 64 + li;
  const double bb = P.dodrop ? (double)P.bias[col] : 0.0;
  double s = 0.0, s2 = 0.0;
#pragma unroll 4
  for (int rr = 0; rr < 16; ++rr) {
    int r = blockIdx.y * 64 + rg * 16 + rr;
    size_t i = (size_t)r * HIDC + col;
    double v = (double)J.Z[i];
    if (J.Zpart) v += (double)J.Zpart[i];
    if (P.dodrop) v = (J.msk[i] >= 0.5f) ? 2.0 * (v + bb) : 0.0;
    s += v;
    s2 += v * v;
  }
  sm[rg][li] = s;
  sq[rg][li] = s2;
  __syncthreads();
  if (rg == 0) {
    double S = sm[0][li] + sm[1][li] + sm[2][li] + sm[3][li];
    double S2 = sq[0][li] + sq[1][li] + sq[2][li] + sq[3][li];
    size_t o = ((size_t)(z * 8 + blockIdx.y) * 2) * HIDC + col;
    P.ppart[o] = S;
    P.ppart[o + HIDC] = S2;
  }
}

__global__ __launch_bounds__(256) void k_stats_fin(const double* __restrict__ ppart,
                                                   double* __restrict__ stats) {
  const int z = blockIdx.z;
  const int c = blockIdx.x * 256 + threadIdx.x;
  double S = 0.0, S2 = 0.0;
#pragma unroll
  for (int y = 0; y < 8; ++y) {
    size_t o = ((size_t)(z * 8 + y) * 2) * HIDC + c;
    S += ppart[o];
    S2 += ppart[o + HIDC];
  }
  double m = S / 512.0;
  double var = S2 / 512.0 - m * m;
  stats[z * 2 * HIDC + c] = m;
  stats[z * 2 * HIDC + HIDC + c] = 1.0 / sqrt(var + 1e-5);
}

// ---------------------------------------------------------------------------
// BN (+optional dropout) + hardtanh, fp64 math; dual-path via grid.z.
// auxmode: 0 -> aux = sign(out) fp16 ; 1 -> aux = fp16(out) ; 2 -> none.
struct BnJob { float* Z; const float* Zpart; _Float16* aux; const float* msk; int auxmode; };
struct Bn2 {
  BnJob j[2];
  const double* stats;
  const float* g; const float* be; const float* bias;
  int dodrop;
};

__global__ __launch_bounds__(256) void k_bn2(Bn2 P) {
  const int z = blockIdx.z;
  BnJob J = z ? P.j[1] : P.j[0];
  const double* m_arr = P.stats + (size_t)z * 2 * HIDC;
  const double* r_arr = m_arr + HIDC;
  int idx = blockIdx.x * 256 + threadIdx.x;  // 512*1536 float4 positions
  int row = idx / 1536;
  int c4 = (idx - row * 1536) * 4;
  size_t base = (size_t)row * HIDC + c4;
  float4 zv = *(const float4*)(J.Z + base);
  float zz[4] = {zv.x, zv.y, zv.z, zv.w};
  float zl[4] = {0.f, 0.f, 0.f, 0.f};
  if (J.Zpart) {
    float4 t4 = *(const float4*)(J.Zpart + base);
    zl[0] = t4.x; zl[1] = t4.y; zl[2] = t4.z; zl[3] = t4.w;
  }
  float mk[4] = {1.f, 1.f, 1.f, 1.f};
  if (P.dodrop) {
    float4 t4 = *(const float4*)(J.msk + base);
    mk[0] = t4.x; mk[1] = t4.y; mk[2] = t4.z; mk[3] = t4.w;
  }
  float o[4];
  f16x4 a4;
#pragma unroll
  for (int e = 0; e < 4; ++e) {
    int c = c4 + e;
    double v = (double)zz[e] + (double)zl[e];
    if (P.dodrop) v = (mk[e] >= 0.5f) ? 2.0 * (v + (double)P.bias[c]) : 0.0;
    double bnv = (double)P.g[c] * ((v - m_arr[c]) * r_arr[c]) + (double)P.be[c];
    bnv = bnv > 1.0 ? 1.0 : (bnv < -1.0 ? -1.0 : bnv);
    o[e] = (float)bnv;
    if (J.auxmode == 0)
      a4[e] = bnv > 0.0 ? (_Float16)1.0f : (bnv < 0.0 ? (_Float16)(-1.0f) : (_Float16)0.0f);
    else
      a4[e] = (_Float16)o[e];
  }
  float4 ov = {o[0], o[1], o[2], o[3]};
  *(float4*)(J.Z + base) = ov;
  if (J.auxmode < 2) *(f16x4*)(J.aux + base) = a4;
}

// ---------------------------------------------------------------------------
// Head: out = Bout3 @ w4^T + b4 (512x10, K=6144) + log_softmax, one block/row.
__global__ __launch_bounds__(256) void k_head(const float* __restrict__ B3,
                                              const float* __restrict__ w4,
                                              const float* __restrict__ b4,
                                              float* __restrict__ out,
                                              float* __restrict__ logp) {
  const int row = blockIdx.x, t = threadIdx.x;
  float acc[10];
#pragma unroll
  for (int j = 0; j < 10; ++j) acc[j] = 0.f;
  const float* a = B3 + (size_t)row * HIDC;
  for (int k4 = t; k4 < 1536; k4 += 256) {
    float4 av = *(const float4*)(a + k4 * 4);
#pragma unroll
    for (int j = 0; j < 10; ++j) {
      float4 wv = *(const float4*)(w4 + (size_t)j * HIDC + k4 * 4);
      acc[j] += av.x * wv.x + av.y * wv.y + av.z * wv.z + av.w * wv.w;
    }
  }
#pragma unroll
  for (int j = 0; j < 10; ++j)
    for (int off = 32; off; off >>= 1) acc[j] += __shfl_down(acc[j], off);
  __shared__ float sred[4][10];
  int wid = t >> 6, ln = t & 63;
  if (ln == 0)
#pragma unroll
    for (int j = 0; j < 10; ++j) sred[wid][j] = acc[j];
  __syncthreads();
  if (t == 0) {
    double o[10];
    double mx = -1e300;
#pragma unroll
    for (int j = 0; j < 10; ++j) {
      o[j] = (double)sred[0][j] + sred[1][j] + sred[2][j] + sred[3][j] + (double)b4[j];
      mx = o[j] > mx ? o[j] : mx;
    }
    double s = 0.0;
#pragma unroll
    for (int j = 0; j < 10; ++j) s += exp(o[j] - mx);
    double l = log(s) + mx;
#pragma unroll
    for (int j = 0; j < 10; ++j) {
      out[row * 10 + j] = (float)o[j];
      logp[row * 10 + j] = (float)(o[j] - l);
    }
  }
}

// ===========================================================================
// ============ round-1 fallback kernels (used when ws too small) ============
template <int MODE>
__global__ __launch_bounds__(256) void k_gemm(const _Float16* __restrict__ A0,
                                              const _Float16* __restrict__ A1,
                                              const float* __restrict__ W,
                                              float* __restrict__ Zb,
                                              float* __restrict__ Zr,
                                              int KA, int KW, int ksteps) {
  __shared__ __align__(16) char smem[49152];
  const int t = threadIdx.x;
  const int lane = t & 63, wn = t >> 6;
  const int bn = blockIdx.x, bm = blockIdx.y;
  f32x4 accB[4][2];
  f32x4 accR[4][2];
#pragma unroll
  for (int mf = 0; mf < 4; ++mf)
#pragma unroll
    for (int nf = 0; nf < 2; ++nf) {
      accB[mf][nf] = (f32x4){0.f, 0.f, 0.f, 0.f};
      accR[mf][nf] = (f32x4){0.f, 0.f, 0.f, 0.f};
    }
  for (int kt = 0; kt < ksteps; ++kt) {
    const int k0 = kt * 64;
#pragma unroll
    for (int i = 0; i < 2; ++i) {
      int p = i * 256 + t;
      int r = p >> 3, k8 = p & 7;
      size_t gi = (size_t)(bm * 64 + r) * KA + k0 + k8 * 8;
      int bo = (r * 128 + k8 * 16) ^ ((r & 7) << 4);
      *(f16x8*)(smem + bo) = *(const f16x8*)(A0 + gi);
      if constexpr (MODE == 1) *(f16x8*)(smem + 8192 + bo) = *(const f16x8*)(A1 + gi);
    }
#pragma unroll
    for (int i = 0; i < 8; ++i) {
      int p = i * 256 + t;
      int r = p >> 4, c4 = p & 15;
      float4 wv = {0.f, 0.f, 0.f, 0.f};
      if (k0 + c4 * 4 < KW)
        wv = *(const float4*)(W + (size_t)(bn * 128 + r) * KW + k0 + c4 * 4);
      float arr[4] = {wv.x, wv.y, wv.z, wv.w};
      f16x4 hv, hs;
#pragma unroll
      for (int e = 0; e < 4; ++e) {
        hv[e] = (_Float16)arr[e];
        hs[e] = arr[e] > 0.f ? (_Float16)1.0f : (arr[e] < 0.f ? (_Float16)(-1.0f) : (_Float16)0.0f);
      }
      int bo = (r * 128 + c4 * 8) ^ ((r & 7) << 4);
      if constexpr (MODE == 1) *(f16x4*)(smem + 16384 + bo) = hs;
      *(f16x4*)(smem + 32768 + bo) = hv;
    }
    __syncthreads();
#pragma unroll
    for (int kk = 0; kk < 2; ++kk) {
      f16x8 a0[4], a1[4], b0[2], b1[2];
#pragma unroll
      for (int mf = 0; mf < 4; ++mf) {
        int r = mf * 16 + (lane & 15);
        int bo = (r * 128 + kk * 64 + (lane >> 4) * 16) ^ ((r & 7) << 4);
        a0[mf] = *(const f16x8*)(smem + bo);
        if constexpr (MODE == 1) a1[mf] = *(const f16x8*)(smem + 8192 + bo);
      }
#pragma unroll
      for (int nf = 0; nf < 2; ++nf) {
        int r = wn * 32 + nf * 16 + (lane & 15);
        int bo = (r * 128 + kk * 64 + (lane >> 4) * 16) ^ ((r & 7) << 4);
        if constexpr (MODE == 1) b0[nf] = *(const f16x8*)(smem + 16384 + bo);
        b1[nf] = *(const f16x8*)(smem + 32768 + bo);
      }
#pragma unroll
      for (int mf = 0; mf < 4; ++mf)
#pragma unroll
        for (int nf = 0; nf < 2; ++nf) {
          if constexpr (MODE == 1) {
            accB[mf][nf] = MFMA16(a0[mf], b0[nf], accB[mf][nf]);
            accR[mf][nf] = MFMA16(a1[mf], b1[nf], accR[mf][nf]);
          } else {
            accR[mf][nf] = MFMA16(a0[mf], b1[nf], accR[mf][nf]);
          }
        }
    }
    __syncthreads();
  }
#pragma unroll
  for (int mf = 0; mf < 4; ++mf)
#pragma unroll
    for (int nf = 0; nf < 2; ++nf) {
      int col = bn * 128 + wn * 32 + nf * 16 + (lane & 15);
      int row0 = bm * 64 + mf * 16 + ((lane >> 4) << 2);
#pragma unroll
      for (int rr = 0; rr < 4; ++rr) {
        size_t o = (size_t)(row0 + rr) * HIDC + col;
        if constexpr (MODE == 1) Zb[o] = accB[mf][nf][rr];
        Zr[o] = accR[mf][nf][rr];
      }
    }
}

__global__ __launch_bounds__(256) void k_stats(const float* __restrict__ Z,
                                               const float* __restrict__ Zlo,
                                               const float* __restrict__ msk,
                                               const float* __restrict__ bias,
                                               int dodrop,
                                               double* __restrict__ m_out,
                                               double* __restrict__ r_out) {
  __shared__ double sm[4][64];
  __shared__ double sq[4][64];
  const int li = threadIdx.x & 63, rg = threadIdx.x >> 6;
  const int c = blockIdx.x * 64 + li;
  const double bb = dodrop ? (double)bias[c] : 0.0;
  double s = 0.0, s2 = 0.0;
  for (int r = rg; r < BATCH; r += 4) {
    size_t i = (size_t)r * HIDC + c;
    double v = (double)Z[i];
    if (Zlo) v += (double)Zlo[i];
    if (dodrop) v = (msk[i] >= 0.5f) ? 2.0 * (v + bb) : 0.0;
    s += v;
    s2 += v * v;
  }
  sm[rg][li] = s;
  sq[rg][li] = s2;
  __syncthreads();
  if (rg == 0) {
    double S = sm[0][li] + sm[1][li] + sm[2][li] + sm[3][li];
    double S2 = sq[0][li] + sq[1][li] + sq[2][li] + sq[3][li];
    double m = S / 512.0;
    double var = S2 / 512.0 - m * m;
    m_out[c] = m;
    r_out[c] = 1.0 / sqrt(var + 1e-5);
  }
}

__global__ __launch_bounds__(256) void k_bn(float* __restrict__ Z,
                                            const float* __restrict__ Zlo,
                                            const double* __restrict__ m_arr,
                                            const double* __restrict__ r_arr,
                                            const float* __restrict__ g,
                                            const float* __restrict__ be,
                                            _Float16* __restrict__ aux, int auxmode,
                                            const float* __restrict__ msk,
                                            const float* __restrict__ bias, int dodrop) {
  int idx = blockIdx.x * 256 + threadIdx.x;
  int row = idx / 1536;
  int c4 = (idx - row * 1536) * 4;
  size_t base = (size_t)row * HIDC + c4;
  float4 z = *(const float4*)(Z + base);
  float zz[4] = {z.x, z.y, z.z, z.w};
  float zl[4] = {0.f, 0.f, 0.f, 0.f};
  if (Zlo) {
    float4 t4 = *(const float4*)(Zlo + base);
    zl[0] = t4.x; zl[1] = t4.y; zl[2] = t4.z; zl[3] = t4.w;
  }
  float mk[4] = {1.f, 1.f, 1.f, 1.f};
  if (dodrop) {
    float4 t4 = *(const float4*)(msk + base);
    mk[0] = t4.x; mk[1] = t4.y; mk[2] = t4.z; mk[3] = t4.w;
  }
  float o[4];
  f16x4 a4;
#pragma unroll
  for (int e = 0; e < 4; ++e) {
    int c = c4 + e;
    double v = (double)zz[e] + (double)zl[e];
    if (dodrop) v = (mk[e] >= 0.5f) ? 2.0 * (v + (double)bias[c]) : 0.0;
    double bnv = (double)g[c] * ((v - m_arr[c]) * r_arr[c]) + (double)be[c];
    bnv = bnv > 1.0 ? 1.0 : (bnv < -1.0 ? -1.0 : bnv);
    o[e] = (float)bnv;
    if (auxmode == 0)
      a4[e] = bnv > 0.0 ? (_Float16)1.0f : (bnv < 0.0 ? (_Float16)(-1.0f) : (_Float16)0.0f);
    else
      a4[e] = (_Float16)o[e];
  }
  float4 ov = {o[0], o[1], o[2], o[3]};
  *(float4*)(Z + base) = ov;
  if (auxmode < 2) *(f16x4*)(aux + base) = a4;
}

// ===========================================================================
extern "C" void kernel_launch(void* const* d_in, const int* in_sizes, int n_in,
                              void* d_out, int out_size, void* d_ws, size_t ws_size,
                              hipStream_t stream) {
  const float* x   = (const float*)d_in[0];
  const float* mkb = (const float*)d_in[1];
  const float* mkr = (const float*)d_in[2];
  const float* w1  = (const float*)d_in[3];
  const float* w2  = (const float*)d_in[5];
  const float* w3  = (const float*)d_in[7];
  const float* b3  = (const float*)d_in[8];
  const float* w4  = (const float*)d_in[9];
  const float* b4  = (const float*)d_in[10];
  const float* g1  = (const float*)d_in[11]; const float* be1 = (const float*)d_in[12];
  const float* g2  = (const float*)d_in[13]; const float* be2 = (const float*)d_in[14];
  const float* g3  = (const float*)d_in[15]; const float* be3 = (const float*)d_in[16];

  float* outp = (float*)d_out;
  float* logp = outp;
  float* outo = outp + 5120;
  float* B1 = outp + 10240;
  float* R1 = outp + 3155968;
  float* B2 = outp + 6301696;
  float* R2 = outp + 9447424;
  float* B3 = outp + 12593152;
  float* R3 = outp + 15738880;

  char* ws = (char*)d_ws;
  _Float16* xh  = (_Float16*)(ws + OFF_XH);
  float* z1lo   = (float*)(ws + OFF_Z1LO);
  _Float16* sB  = (_Float16*)(ws + OFF_SB);
  _Float16* rF  = (_Float16*)(ws + OFF_RF);
  double* stats = (double*)(ws + OFF_STATS);

  if (ws_size >= WS_NEED) {
    double* ppart = (double*)(ws + OFF_PPART);
    float* zpb    = (float*)(ws + OFF_ZPB);
    float* zpr    = (float*)(ws + OFF_ZPR);
    _Float16* w1v = (_Float16*)(ws + OFF_W1V);
    _Float16* wv  = (_Float16*)(ws + OFF_WV);
    _Float16* wsg = (_Float16*)(ws + OFF_WS2);

    // ---- layer 1 ----
    k_prep_x<<<416, 256, 0, stream>>>(x, xh);
    k_conv_w1<<<2496, 256, 0, stream>>>(w1, w1v);
    k_gemm64<<<dim3(96, 8), 256, 0, stream>>>(x, w1, B1, z1lo);
    {
      Gemm4 P{};
      P.j[0] = {xh, w1v, R1, 832, 0, 13};
      P.j[1] = P.j[0]; P.j[2] = P.j[0]; P.j[3] = P.j[0];
      k_gemm16<<<dim3(48, 4, 1), 256, 0, stream>>>(P);
    }
    {
      St2 S{}; S.j[0] = {B1, z1lo, nullptr}; S.j[1] = {R1, nullptr, nullptr};
      S.bias = nullptr; S.dodrop = 0; S.ppart = ppart;
      k_stats_part<<<dim3(96, 8, 2), 256, 0, stream>>>(S);
      k_stats_fin<<<dim3(24, 1, 2), 256, 0, stream>>>(ppart, stats);
      Bn2 B{}; B.j[0] = {B1, z1lo, sB, nullptr, 0}; B.j[1] = {R1, nullptr, rF, nullptr, 1};
      B.stats = stats; B.g = g1; B.be = be1; B.bias = nullptr; B.dodrop = 0;
      k_bn2<<<dim3(3072, 1, 2), 256, 0, stream>>>(B);
    }
    // ---- layer 2 ----
    k_conv_w23<<<18432, 256, 0, stream>>>(w2, wv, wsg);
    {
      Gemm4 P{};
      P.j[0] = {sB, wsg, B2, HIDC, 0, 48};
      P.j[1] = {sB, wsg, zpb, HIDC, 3072, 48};
      P.j[2] = {rF, wv, R2, HIDC, 0, 48};
      P.j[3] = {rF, wv, zpr, HIDC, 3072, 48};
      k_gemm16<<<dim3(48, 4, 4), 256, 0, stream>>>(P);
    }
    {
      St2 S{}; S.j[0] = {B2, zpb, nullptr}; S.j[1] = {R2, zpr, nullptr};
      S.bias = nullptr; S.dodrop = 0; S.ppart = ppart;
      k_stats_part<<<dim3(96, 8, 2), 256, 0, stream>>>(S);
      k_stats_fin<<<dim3(24, 1, 2), 256, 0, stream>>>(ppart, stats);
      Bn2 B{}; B.j[0] = {B2, zpb, sB, nullptr, 0}; B.j[1] = {R2, zpr, rF, nullptr, 1};
      B.stats = stats; B.g = g2; B.be = be2; B.bias = nullptr; B.dodrop = 0;
      k_bn2<<<dim3(3072, 1, 2), 256, 0, stream>>>(B);
    }
    // ---- layer 3 ----
    k_conv_w23<<<18432, 256, 0, stream>>>(w3, wv, wsg);
    {
      Gemm4 P{};
      P.j[0] = {sB, wsg, B3, HIDC, 0, 48};
      P.j[1] = {sB, wsg, zpb, HIDC, 3072, 48};
      P.j[2] = {rF, wv, R3, HIDC, 0, 48};
      P.j[3] = {rF, wv, zpr, HIDC, 3072, 48};
      k_gemm16<<<dim3(48, 4, 4), 256, 0, stream>>>(P);
    }
    {
      St2 S{}; S.j[0] = {B3, zpb, mkb}; S.j[1] = {R3, zpr, mkr};
      S.bias = b3; S.dodrop = 1; S.ppart = ppart;
      k_stats_part<<<dim3(96, 8, 2), 256, 0, stream>>>(S);
      k_stats_fin<<<dim3(24, 1, 2), 256, 0, stream>>>(ppart, stats);
      Bn2 B{}; B.j[0] = {B3, zpb, nullptr, mkb, 2}; B.j[1] = {R3, zpr, nullptr, mkr, 2};
      B.stats = stats; B.g = g3; B.be = be3; B.bias = b3; B.dodrop = 1;
      k_bn2<<<dim3(3072, 1, 2), 256, 0, stream>>>(B);
    }
    k_head<<<512, 256, 0, stream>>>(B3, w4, b4, outo, logp);
  } else {
    // ---------- round-1 fallback ----------
    double* m_b = stats; double* r_b = stats + 6144;
    double* m_r = stats + 12288; double* r_r = stats + 18432;
    k_prep_x<<<416, 256, 0, stream>>>(x, xh);
    k_gemm64<<<dim3(96, 8), 256, 0, stream>>>(x, w1, B1, z1lo);
    k_gemm<0><<<dim3(48, 8), 256, 0, stream>>>(xh, nullptr, w1, nullptr, R1, 832, 784, 13);
    k_stats<<<96, 256, 0, stream>>>(B1, z1lo, nullptr, nullptr, 0, m_b, r_b);
    k_stats<<<96, 256, 0, stream>>>(R1, nullptr, nullptr, nullptr, 0, m_r, r_r);
    k_bn<<<3072, 256, 0, stream>>>(B1, z1lo, m_b, r_b, g1, be1, sB, 0, nullptr, nullptr, 0);
    k_bn<<<3072, 256, 0, stream>>>(R1, nullptr, m_r, r_r, g1, be1, rF, 1, nullptr, nullptr, 0);
    k_gemm<1><<<dim3(48, 8), 256, 0, stream>>>(sB, rF, w2, B2, R2, 6144, 6144, 96);
    k_stats<<<96, 256, 0, stream>>>(B2, nullptr, nullptr, nullptr, 0, m_b, r_b);
    k_stats<<<96, 256, 0, stream>>>(R2, nullptr, nullptr, nullptr, 0, m_r, r_r);
    k_bn<<<3072, 256, 0, stream>>>(B2, nullptr, m_b, r_b, g2, be2, sB, 0, nullptr, nullptr, 0);
    k_bn<<<3072, 256, 0, stream>>>(R2, nullptr, m_r, r_r, g2, be2, rF, 1, nullptr, nullptr, 0);
    k_gemm<1><<<dim3(48, 8), 256, 0, stream>>>(sB, rF, w3, B3, R3, 6144, 6144, 96);
    k_stats<<<96, 256, 0, stream>>>(B3, nullptr, mkb, b3, 1, m_b, r_b);
    k_stats<<<96, 256, 0, stream>>>(R3, nullptr, mkr, b3, 1, m_r, r_r);
    k_bn<<<3072, 256, 0, stream>>>(B3, nullptr, m_b, r_b, g3, be3, nullptr, 2, mkb, b3, 1);
    k_bn<<<3072, 256, 0, stream>>>(R3, nullptr, m_r, r_r, g3, be3, nullptr, 2, mkr, b3, 1);
    k_head<<<512, 256, 0, stream>>>(B3, w4, b4, outo, logp);
  }
}

// Round 5
// 669.924 us; speedup vs baseline: 2.6698x; 1.2687x over previous
//
#include <hip/hip_runtime.h>

// Binarized MLP forward (512x784 -> 3x6144 -> 10), dual binary/real paths.
// Round 5 (= round 4 + compile fix in fallback k_gemm):
// layer-1 binary GEMM via exact i8-MFMA digit decomposition:
//   q = rint(x * 2^24)  (int, |q| < 2^27)
//   q = d0 + 256*d1 + 65536*d2 + 16777216*d3,  d_i in [-128,127]
//   Z = (sum_i 256^i * (D_i = d_i @ sign(w1)^T)) * 2^-24   -- all exact
//
// Precision plan (validated rounds 1-2):
//  - layer1 binary: exact integer MFMA + fp64 combine, hi/lo fp32 storage
//  - layer2/3 binary: fp16 MFMA, EXACT (+-1 products, integer fp32 sums < 2^24)
//  - real path: fp16 MFMA (error ~1e-3 << 2% thresholds)
//  - all batch-norm stats and normalization in fp64

typedef _Float16 f16x8 __attribute__((ext_vector_type(8)));
typedef _Float16 f16x4 __attribute__((ext_vector_type(4)));
typedef float f32x4 __attribute__((ext_vector_type(4)));
typedef int i32x4 __attribute__((ext_vector_type(4)));

#define MFMA16(a, b, c) __builtin_amdgcn_mfma_f32_16x16x32_f16((a), (b), (c), 0, 0, 0)
#define MFMAI8(a, b, c) __builtin_amdgcn_mfma_i32_16x16x32_i8((a), (b), (c), 0, 0, 0)

#define HIDC 6144
#define BATCH 512

// ---- workspace layout (bytes) ----
#define OFF_XH    0ull          // 512x832 fp16                    851,968
#define OFF_Z1LO  851968ull     // 512x6144 fp32                12,582,912
#define OFF_SB    13434880ull   // 512x6144 fp16                 6,291,456
#define OFF_RF    19726336ull   // 512x6144 fp16                 6,291,456
#define OFF_STATS 26017792ull   // 4x6144 fp64                     196,608
#define OFF_PPART 26214400ull   // 2x8x2x6144 fp64               1,572,864
#define OFF_ZPB   27787264ull   // 512x6144 fp32 (splitK bin / D0)  12,582,912
#define OFF_ZPR   40370176ull   // 512x6144 fp32 (splitK real / D1) 12,582,912
#define OFF_W1V   52953088ull   // 6144x832 fp16                10,223,616
#define OFF_WV    63176704ull   // 6144x6144 fp16 (D2/D3 during L1) 75,497,472
#define OFF_WS2   138674176ull  // 6144x6144 fp16 (digit/sign planes during L1)
#define WS_NEED   214171648ull

// layer-1 scratch carved from regions free during layer 1:
#define A8_STRIDE 425984ull     // 512*832 bytes per digit plane

// ---------------------------------------------------------------------------
__device__ __forceinline__ void load_lds16(const void* g, char* lds) {
  __builtin_amdgcn_global_load_lds((const __attribute__((address_space(1))) void*)g,
                                   (__attribute__((address_space(3))) void*)lds, 16, 0, 0);
}

// ---------------------------------------------------------------------------
// x (512x784 fp32) -> xh (512x832 fp16, zero-padded cols 784..831)
__global__ __launch_bounds__(256) void k_prep_x(const float* __restrict__ x,
                                                _Float16* __restrict__ xh) {
  int idx = blockIdx.x * 256 + threadIdx.x;  // over 512*208 float4 positions
  if (idx >= 512 * 208) return;
  int row = idx / 208, c4 = idx - row * 208;
  f16x4 h;
  if (c4 < 196) {
    float4 v = *(const float4*)(x + (size_t)row * 784 + c4 * 4);
    h[0] = (_Float16)v.x; h[1] = (_Float16)v.y; h[2] = (_Float16)v.z; h[3] = (_Float16)v.w;
  } else {
    h[0] = (_Float16)0.f; h[1] = (_Float16)0.f; h[2] = (_Float16)0.f; h[3] = (_Float16)0.f;
  }
  *(f16x4*)(xh + (size_t)row * 832 + c4 * 4) = h;
}

// ---------------------------------------------------------------------------
// x (512x784 fp32) -> 4 signed base-256 digit planes of rint(x*2^24),
// each [512][832] i8, zero-padded cols 784..831.
__global__ __launch_bounds__(256) void k_quant_x(const float* __restrict__ x,
                                                 char* __restrict__ a8) {
  int idx = blockIdx.x * 256 + threadIdx.x;  // 512*832 = 425984
  if (idx >= 512 * 832) return;
  int row = idx / 832, k = idx - row * 832;
  float v = (k < 784) ? x[(size_t)row * 784 + k] : 0.f;
  int q = (int)lrintf(v * 16777216.0f);
  int d0 = ((q + 128) & 255) - 128; q = (q - d0) >> 8;
  int d1 = ((q + 128) & 255) - 128; q = (q - d1) >> 8;
  int d2 = ((q + 128) & 255) - 128; q = (q - d2) >> 8;
  a8[idx] = (char)d0;
  a8[A8_STRIDE + idx] = (char)d1;
  a8[2 * A8_STRIDE + idx] = (char)d2;
  a8[3 * A8_STRIDE + idx] = (char)q;  // |q| <= 9
}

// ---------------------------------------------------------------------------
// w1 (6144x784 fp32) -> s1 (6144x832 i8 sign, zero-padded)
__global__ __launch_bounds__(256) void k_sign_w1(const float* __restrict__ w,
                                                 char* __restrict__ s1) {
  int idx = blockIdx.x * 256 + threadIdx.x;  // 6144*832
  if (idx >= 6144 * 832) return;
  int r = idx / 832, k = idx - r * 832;
  char s = 0;
  if (k < 784) {
    float v = w[(size_t)r * 784 + k];
    s = v > 0.f ? 1 : (v < 0.f ? -1 : 0);
  }
  s1[idx] = s;
}

// ---------------------------------------------------------------------------
// w1 (6144x784 fp32) -> W1v (6144x832 fp16, zero-padded) [real path]
__global__ __launch_bounds__(256) void k_conv_w1(const float* __restrict__ w,
                                                 _Float16* __restrict__ wv) {
  int idx = blockIdx.x * 256 + threadIdx.x;  // 6144*104 f16x8 groups
  if (idx >= 6144 * 104) return;
  int r = idx / 104, c8 = idx - r * 104;
  f16x8 hv;
  if (c8 < 98) {
    const float* s = w + (size_t)r * 784 + c8 * 8;
    float4 v0 = *(const float4*)s;
    float4 v1 = *(const float4*)(s + 4);
    float a[8] = {v0.x, v0.y, v0.z, v0.w, v1.x, v1.y, v1.z, v1.w};
#pragma unroll
    for (int e = 0; e < 8; ++e) hv[e] = (_Float16)a[e];
  } else {
#pragma unroll
    for (int e = 0; e < 8; ++e) hv[e] = (_Float16)0.f;
  }
  *(f16x8*)(wv + (size_t)r * 832 + c8 * 8) = hv;
}

// ---------------------------------------------------------------------------
// w (6144x6144 fp32) -> Wv (fp16 value), Wsg (fp16 sign)
__global__ __launch_bounds__(256) void k_conv_w23(const float* __restrict__ w,
                                                  _Float16* __restrict__ wv,
                                                  _Float16* __restrict__ wsg) {
  int idx = blockIdx.x * 256 + threadIdx.x;  // 6144*768 f16x8 groups
  size_t o8 = (size_t)idx * 8;
  const float* s = w + o8;
  float4 v0 = *(const float4*)s;
  float4 v1 = *(const float4*)(s + 4);
  float a[8] = {v0.x, v0.y, v0.z, v0.w, v1.x, v1.y, v1.z, v1.w};
  f16x8 hv, hs;
#pragma unroll
  for (int e = 0; e < 8; ++e) {
    hv[e] = (_Float16)a[e];
    hs[e] = a[e] > 0.f ? (_Float16)1.0f : (a[e] < 0.f ? (_Float16)(-1.0f) : (_Float16)0.0f);
  }
  *(f16x8*)(wv + o8) = hv;
  *(f16x8*)(wsg + o8) = hs;
}

// ---------------------------------------------------------------------------
// i8 GEMM: D_z[512 x 6144] (i32) = digit_z(x) [512x832] @ s1[6144x832]^T.
// BM=BN=128, BK=64, 4 waves (2x2), global_load_lds, m97 2-barrier loop.
// grid (48, 4, 4): z = digit plane.
__global__ __launch_bounds__(256) void k_gemm_i8(const char* __restrict__ a8,
                                                 const char* __restrict__ s1,
                                                 int* __restrict__ D0,
                                                 int* __restrict__ D1,
                                                 int* __restrict__ D2,
                                                 int* __restrict__ D3) {
  __shared__ __align__(16) char smem[16384];  // A @0 (8K), B @8192 (8K)
  const int z = blockIdx.z;
  const char* A = a8 + (size_t)z * A8_STRIDE;
  int* C = D0;
  if (z == 1) C = D1;
  if (z == 2) C = D2;
  if (z == 3) C = D3;
  const int t = threadIdx.x;
  const int lane = t & 63, wid = t >> 6;
  const int wm = wid >> 1, wn = wid & 1;
  const int bn = blockIdx.x, bm = blockIdx.y;

  i32x4 acc[4][4];
#pragma unroll
  for (int mf = 0; mf < 4; ++mf)
#pragma unroll
    for (int nf = 0; nf < 4; ++nf) acc[mf][nf] = (i32x4){0, 0, 0, 0};

  for (int kt = 0; kt < 13; ++kt) {
    const int k0 = kt * 64;
#pragma unroll
    for (int i = 0; i < 2; ++i) {
      int p = i * 256 + t;
      int r = p >> 2, c16 = p & 3;
      load_lds16(A + (size_t)(bm * 128 + r) * 832 + k0 + c16 * 16, smem + p * 16);
    }
#pragma unroll
    for (int i = 0; i < 2; ++i) {
      int p = i * 256 + t;
      int r = p >> 2, c16 = p & 3;
      load_lds16(s1 + (size_t)(bn * 128 + r) * 832 + k0 + c16 * 16, smem + 8192 + p * 16);
    }
    __syncthreads();
#pragma unroll
    for (int kk = 0; kk < 2; ++kk) {  // two K=32 halves of BK=64
      long av[4], bv[4];
#pragma unroll
      for (int mf = 0; mf < 4; ++mf) {
        int r = wm * 64 + mf * 16 + (lane & 15);
        av[mf] = *(const long*)(smem + r * 64 + kk * 32 + (lane >> 4) * 8);
      }
#pragma unroll
      for (int nf = 0; nf < 4; ++nf) {
        int r = wn * 64 + nf * 16 + (lane & 15);
        bv[nf] = *(const long*)(smem + 8192 + r * 64 + kk * 32 + (lane >> 4) * 8);
      }
#pragma unroll
      for (int mf = 0; mf < 4; ++mf)
#pragma unroll
        for (int nf = 0; nf < 4; ++nf) acc[mf][nf] = MFMAI8(av[mf], bv[nf], acc[mf][nf]);
    }
    __syncthreads();
  }
  // D layout (verified dtype-independent): col=lane&15, row=(lane>>4)*4+reg
#pragma unroll
  for (int mf = 0; mf < 4; ++mf)
#pragma unroll
    for (int nf = 0; nf < 4; ++nf) {
      int col = bn * 128 + wn * 64 + nf * 16 + (lane & 15);
      int row0 = bm * 128 + wm * 64 + mf * 16 + ((lane >> 4) << 2);
#pragma unroll
      for (int rr = 0; rr < 4; ++rr) {
        C[(size_t)(row0 + rr) * HIDC + col] = acc[mf][nf][rr];
      }
    }
}

// ---------------------------------------------------------------------------
// Combine digit GEMMs: Z = (((D3*256+D2)*256+D1)*256+D0) * 2^-24, hi/lo fp32.
__global__ __launch_bounds__(256) void k_combine1(const int* __restrict__ D0,
                                                  const int* __restrict__ D1,
                                                  const int* __restrict__ D2,
                                                  const int* __restrict__ D3,
                                                  float* __restrict__ Zhi,
                                                  float* __restrict__ Zlo) {
  size_t i4 = ((size_t)blockIdx.x * 256 + threadIdx.x) * 4;  // 512*6144 elems
  i32x4 v0 = *(const i32x4*)(D0 + i4);
  i32x4 v1 = *(const i32x4*)(D1 + i4);
  i32x4 v2 = *(const i32x4*)(D2 + i4);
  i32x4 v3 = *(const i32x4*)(D3 + i4);
  float4 hi, lo;
  float* hp = &hi.x;
  float* lp = &lo.x;
#pragma unroll
  for (int e = 0; e < 4; ++e) {
    double zv = (((double)v3[e] * 256.0 + (double)v2[e]) * 256.0 + (double)v1[e]) * 256.0 +
                (double)v0[e];
    zv *= (1.0 / 16777216.0);
    float h = (float)zv;
    hp[e] = h;
    lp[e] = (float)(zv - (double)h);
  }
  *(float4*)(Zhi + i4) = hi;
  *(float4*)(Zlo + i4) = lo;
}

// ---------------------------------------------------------------------------
// m97-style fp16 GEMM: C[M x N] = A[M x K] @ B[N x K]^T, BM=BN=128, BK=64,
// 4 waves (2x2), global_load_lds staging, linear LDS, 2-barrier K-loop.
struct GemmJob {
  const _Float16* A;
  const _Float16* B;
  float* C;
  int K;
  int kstart;
  int ksteps;
};
struct Gemm4 { GemmJob j[4]; };

__global__ __launch_bounds__(256) void k_gemm16(Gemm4 P) {
  __shared__ __align__(16) char smem[32768];  // A @0 (16K), B @16384 (16K)
  GemmJob J = P.j[0];
  if (blockIdx.z == 1) J = P.j[1];
  if (blockIdx.z == 2) J = P.j[2];
  if (blockIdx.z == 3) J = P.j[3];
  const int t = threadIdx.x;
  const int lane = t & 63, wid = t >> 6;
  const int wm = wid >> 1, wn = wid & 1;
  const int bn = blockIdx.x, bm = blockIdx.y;
  const size_t K = (size_t)J.K;

  f32x4 acc[4][4];
#pragma unroll
  for (int mf = 0; mf < 4; ++mf)
#pragma unroll
    for (int nf = 0; nf < 4; ++nf) acc[mf][nf] = (f32x4){0.f, 0.f, 0.f, 0.f};

  for (int kt = 0; kt < J.ksteps; ++kt) {
    const int k0 = J.kstart + kt * 64;
#pragma unroll
    for (int i = 0; i < 4; ++i) {
      int p = i * 256 + t;
      int r = p >> 3, c16 = p & 7;
      load_lds16(J.A + (size_t)(bm * 128 + r) * K + k0 + c16 * 8, smem + p * 16);
    }
#pragma unroll
    for (int i = 0; i < 4; ++i) {
      int p = i * 256 + t;
      int r = p >> 3, c16 = p & 7;
      load_lds16(J.B + (size_t)(bn * 128 + r) * K + k0 + c16 * 8, smem + 16384 + p * 16);
    }
    __syncthreads();
#pragma unroll
    for (int kk = 0; kk < 2; ++kk) {
      f16x8 av[4], bv[4];
#pragma unroll
      for (int mf = 0; mf < 4; ++mf) {
        int r = wm * 64 + mf * 16 + (lane & 15);
        av[mf] = *(const f16x8*)(smem + r * 128 + kk * 64 + (lane >> 4) * 16);
      }
#pragma unroll
      for (int nf = 0; nf < 4; ++nf) {
        int r = wn * 64 + nf * 16 + (lane & 15);
        bv[nf] = *(const f16x8*)(smem + 16384 + r * 128 + kk * 64 + (lane >> 4) * 16);
      }
#pragma unroll
      for (int mf = 0; mf < 4; ++mf)
#pragma unroll
        for (int nf = 0; nf < 4; ++nf) acc[mf][nf] = MFMA16(av[mf], bv[nf], acc[mf][nf]);
    }
    __syncthreads();
  }
#pragma unroll
  for (int mf = 0; mf < 4; ++mf)
#pragma unroll
    for (int nf = 0; nf < 4; ++nf) {
      int col = bn * 128 + wn * 64 + nf * 16 + (lane & 15);
      int row0 = bm * 128 + wm * 64 + mf * 16 + ((lane >> 4) << 2);
#pragma unroll
      for (int rr = 0; rr < 4; ++rr) {
        J.C[(size_t)(row0 + rr) * HIDC + col] = acc[mf][nf][rr];
      }
    }
}

// ---------------------------------------------------------------------------
// Two-stage per-column stats (mean, rstd over 512 rows), fp64.
struct StJob { const float* Z; const float* Zpart; const float* msk; };
struct St2 { StJob j[2]; const float* bias; int dodrop; double* ppart; };

__global__ __launch_bounds__(256) void k_stats_part(St2 P) {
  __shared__ double sm[4][64];
  __shared__ double sq[4][64];
  const int z = blockIdx.z;
  StJob J = z ? P.j[1] : P.j[0];
  const int li = threadIdx.x & 63, rg = threadIdx.x >> 6;
  const int col = blockIdx.x * 64 + li;
  const double bb = P.dodrop ? (double)P.bias[col] : 0.0;
  double s = 0.0, s2 = 0.0;
#pragma unroll 4
  for (int rr = 0; rr < 16; ++rr) {
    int r = blockIdx.y * 64 + rg * 16 + rr;
    size_t i = (size_t)r * HIDC + col;
    double v = (double)J.Z[i];
    if (J.Zpart) v += (double)J.Zpart[i];
    if (P.dodrop) v = (J.msk[i] >= 0.5f) ? 2.0 * (v + bb) : 0.0;
    s += v;
    s2 += v * v;
  }
  sm[rg][li] = s;
  sq[rg][li] = s2;
  __syncthreads();
  if (rg == 0) {
    double S = sm[0][li] + sm[1][li] + sm[2][li] + sm[3][li];
    double S2 = sq[0][li] + sq[1][li] + sq[2][li] + sq[3][li];
    size_t o = ((size_t)(z * 8 + blockIdx.y) * 2) * HIDC + col;
    P.ppart[o] = S;
    P.ppart[o + HIDC] = S2;
  }
}

__global__ __launch_bounds__(256) void k_stats_fin(const double* __restrict__ ppart,
                                                   double* __restrict__ stats) {
  const int z = blockIdx.z;
  const int c = blockIdx.x * 256 + threadIdx.x;
  double S = 0.0, S2 = 0.0;
#pragma unroll
  for (int y = 0; y < 8; ++y) {
    size_t o = ((size_t)(z * 8 + y) * 2) * HIDC + c;
    S += ppart[o];
    S2 += ppart[o + HIDC];
  }
  double m = S / 512.0;
  double var = S2 / 512.0 - m * m;
  stats[z * 2 * HIDC + c] = m;
  stats[z * 2 * HIDC + HIDC + c] = 1.0 / sqrt(var + 1e-5);
}

// ---------------------------------------------------------------------------
// BN (+optional dropout) + hardtanh, fp64 math; dual-path via grid.z.
struct BnJob { float* Z; const float* Zpart; _Float16* aux; const float* msk; int auxmode; };
struct Bn2 {
  BnJob j[2];
  const double* stats;
  const float* g; const float* be; const float* bias;
  int dodrop;
};

__global__ __launch_bounds__(256) void k_bn2(Bn2 P) {
  const int z = blockIdx.z;
  BnJob J = z ? P.j[1] : P.j[0];
  const double* m_arr = P.stats + (size_t)z * 2 * HIDC;
  const double* r_arr = m_arr + HIDC;
  int idx = blockIdx.x * 256 + threadIdx.x;  // 512*1536 float4 positions
  int row = idx / 1536;
  int c4 = (idx - row * 1536) * 4;
  size_t base = (size_t)row * HIDC + c4;
  float4 zv = *(const float4*)(J.Z + base);
  float zz[4] = {zv.x, zv.y, zv.z, zv.w};
  float zl[4] = {0.f, 0.f, 0.f, 0.f};
  if (J.Zpart) {
    float4 t4 = *(const float4*)(J.Zpart + base);
    zl[0] = t4.x; zl[1] = t4.y; zl[2] = t4.z; zl[3] = t4.w;
  }
  float mk[4] = {1.f, 1.f, 1.f, 1.f};
  if (P.dodrop) {
    float4 t4 = *(const float4*)(J.msk + base);
    mk[0] = t4.x; mk[1] = t4.y; mk[2] = t4.z; mk[3] = t4.w;
  }
  float o[4];
  f16x4 a4;
#pragma unroll
  for (int e = 0; e < 4; ++e) {
    int c = c4 + e;
    double v = (double)zz[e] + (double)zl[e];
    if (P.dodrop) v = (mk[e] >= 0.5f) ? 2.0 * (v + (double)P.bias[c]) : 0.0;
    double bnv = (double)P.g[c] * ((v - m_arr[c]) * r_arr[c]) + (double)P.be[c];
    bnv = bnv > 1.0 ? 1.0 : (bnv < -1.0 ? -1.0 : bnv);
    o[e] = (float)bnv;
    if (J.auxmode == 0)
      a4[e] = bnv > 0.0 ? (_Float16)1.0f : (bnv < 0.0 ? (_Float16)(-1.0f) : (_Float16)0.0f);
    else
      a4[e] = (_Float16)o[e];
  }
  float4 ov = {o[0], o[1], o[2], o[3]};
  *(float4*)(J.Z + base) = ov;
  if (J.auxmode < 2) *(f16x4*)(J.aux + base) = a4;
}

// ---------------------------------------------------------------------------
// Head: out = Bout3 @ w4^T + b4 (512x10, K=6144) + log_softmax, one block/row.
__global__ __launch_bounds__(256) void k_head(const float* __restrict__ B3,
                                              const float* __restrict__ w4,
                                              const float* __restrict__ b4,
                                              float* __restrict__ out,
                                              float* __restrict__ logp) {
  const int row = blockIdx.x, t = threadIdx.x;
  float acc[10];
#pragma unroll
  for (int j = 0; j < 10; ++j) acc[j] = 0.f;
  const float* a = B3 + (size_t)row * HIDC;
  for (int k4 = t; k4 < 1536; k4 += 256) {
    float4 av = *(const float4*)(a + k4 * 4);
#pragma unroll
    for (int j = 0; j < 10; ++j) {
      float4 wv = *(const float4*)(w4 + (size_t)j * HIDC + k4 * 4);
      acc[j] += av.x * wv.x + av.y * wv.y + av.z * wv.z + av.w * wv.w;
    }
  }
#pragma unroll
  for (int j = 0; j < 10; ++j)
    for (int off = 32; off; off >>= 1) acc[j] += __shfl_down(acc[j], off);
  __shared__ float sred[4][10];
  int wid = t >> 6, ln = t & 63;
  if (ln == 0)
#pragma unroll
    for (int j = 0; j < 10; ++j) sred[wid][j] = acc[j];
  __syncthreads();
  if (t == 0) {
    double o[10];
    double mx = -1e300;
#pragma unroll
    for (int j = 0; j < 10; ++j) {
      o[j] = (double)sred[0][j] + sred[1][j] + sred[2][j] + sred[3][j] + (double)b4[j];
      mx = o[j] > mx ? o[j] : mx;
    }
    double s = 0.0;
#pragma unroll
    for (int j = 0; j < 10; ++j) s += exp(o[j] - mx);
    double l = log(s) + mx;
#pragma unroll
    for (int j = 0; j < 10; ++j) {
      out[row * 10 + j] = (float)o[j];
      logp[row * 10 + j] = (float)(o[j] - l);
    }
  }
}

// ===========================================================================
// ============ round-1 fallback kernels (used when ws too small) ============
__global__ __launch_bounds__(256) void k_gemm64(const float* __restrict__ x,
                                                const float* __restrict__ w1,
                                                float* __restrict__ Zhi,
                                                float* __restrict__ Zlo) {
  __shared__ double xs[64][17];
  __shared__ double wsm[64][17];
  const int t = threadIdx.x;
  const int tx = t & 15, ty = t >> 4;
  const int bn = blockIdx.x, bm = blockIdx.y;
  double acc[4][4] = {};
  for (int kt = 0; kt < 49; ++kt) {
    int k0 = kt * 16;
#pragma unroll
    for (int i = 0; i < 4; ++i) {
      int p = i * 256 + t;
      int r = p >> 4, k = p & 15;
      xs[r][k] = (double)x[(size_t)(bm * 64 + r) * 784 + k0 + k];
      float wv = w1[(size_t)(bn * 64 + r) * 784 + k0 + k];
      wsm[r][k] = wv > 0.f ? 1.0 : (wv < 0.f ? -1.0 : 0.0);
    }
    __syncthreads();
#pragma unroll
    for (int k = 0; k < 16; ++k) {
      double a0 = xs[ty * 4 + 0][k], a1 = xs[ty * 4 + 1][k];
      double a2 = xs[ty * 4 + 2][k], a3 = xs[ty * 4 + 3][k];
      double b0 = wsm[tx * 4 + 0][k], b1 = wsm[tx * 4 + 1][k];
      double b2 = wsm[tx * 4 + 2][k], b3 = wsm[tx * 4 + 3][k];
      acc[0][0] += a0 * b0; acc[0][1] += a0 * b1; acc[0][2] += a0 * b2; acc[0][3] += a0 * b3;
      acc[1][0] += a1 * b0; acc[1][1] += a1 * b1; acc[1][2] += a1 * b2; acc[1][3] += a1 * b3;
      acc[2][0] += a2 * b0; acc[2][1] += a2 * b1; acc[2][2] += a2 * b2; acc[2][3] += a2 * b3;
      acc[3][0] += a3 * b0; acc[3][1] += a3 * b1; acc[3][2] += a3 * b2; acc[3][3] += a3 * b3;
    }
    __syncthreads();
  }
#pragma unroll
  for (int i = 0; i < 4; ++i)
#pragma unroll
    for (int j = 0; j < 4; ++j) {
      double v = acc[i][j];
      float h = (float)v;
      float l = (float)(v - (double)h);
      size_t o = (size_t)(bm * 64 + ty * 4 + i) * HIDC + bn * 64 + tx * 4 + j;
      Zhi[o] = h;
      Zlo[o] = l;
    }
}

template <int MODE>
__global__ __launch_bounds__(256) void k_gemm(const _Float16* __restrict__ A0,
                                              const _Float16* __restrict__ A1,
                                              const float* __restrict__ W,
                                              float* __restrict__ Zb,
                                              float* __restrict__ Zr,
                                              int KA, int KW, int ksteps) {
  __shared__ __align__(16) char smem[49152];
  const int t = threadIdx.x;
  const int lane = t & 63, wn = t >> 6;
  const int bn = blockIdx.x, bm = blockIdx.y;
  f32x4 accB[4][2];
  f32x4 accR[4][2];
#pragma unroll
  for (int mf = 0; mf < 4; ++mf)
#pragma unroll
    for (int nf = 0; nf < 2; ++nf) {
      accB[mf][nf] = (f32x4){0.f, 0.f, 0.f, 0.f};
      accR[mf][nf] = (f32x4){0.f, 0.f, 0.f, 0.f};
    }
  for (int kt = 0; kt < ksteps; ++kt) {
    const int k0 = kt * 64;
#pragma unroll
    for (int i = 0; i < 2; ++i) {
      int p = i * 256 + t;
      int r = p >> 3, k8 = p & 7;
      size_t gi = (size_t)(bm * 64 + r) * KA + k0 + k8 * 8;
      int bo = (r * 128 + k8 * 16) ^ ((r & 7) << 4);
      *(f16x8*)(smem + bo) = *(const f16x8*)(A0 + gi);
      if constexpr (MODE == 1) *(f16x8*)(smem + 8192 + bo) = *(const f16x8*)(A1 + gi);
    }
#pragma unroll
    for (int i = 0; i < 8; ++i) {
      int p = i * 256 + t;
      int r = p >> 4, c4 = p & 15;
      float4 wv = {0.f, 0.f, 0.f, 0.f};
      if (k0 + c4 * 4 < KW)
        wv = *(const float4*)(W + (size_t)(bn * 128 + r) * KW + k0 + c4 * 4);
      float arr[4] = {wv.x, wv.y, wv.z, wv.w};
      f16x4 hv, hs;
#pragma unroll
      for (int e = 0; e < 4; ++e) {
        hv[e] = (_Float16)arr[e];
        hs[e] = arr[e] > 0.f ? (_Float16)1.0f : (arr[e] < 0.f ? (_Float16)(-1.0f) : (_Float16)0.0f);
      }
      int bo = (r * 128 + c4 * 8) ^ ((r & 7) << 4);
      if constexpr (MODE == 1) *(f16x4*)(smem + 16384 + bo) = hs;
      *(f16x4*)(smem + 32768 + bo) = hv;
    }
    __syncthreads();
#pragma unroll
    for (int kk = 0; kk < 2; ++kk) {
      f16x8 a0[4], a1[4], b0[2], b1[2];
#pragma unroll
      for (int mf = 0; mf < 4; ++mf) {
        int r = mf * 16 + (lane & 15);
        int bo = (r * 128 + kk * 64 + (lane >> 4) * 16) ^ ((r & 7) << 4);
        a0[mf] = *(const f16x8*)(smem + bo);
        if constexpr (MODE == 1) a1[mf] = *(const f16x8*)(smem + 8192 + bo);
      }
#pragma unroll
      for (int nf = 0; nf < 2; ++nf) {
        int r = wn * 32 + nf * 16 + (lane & 15);
        int bo = (r * 128 + kk * 64 + (lane >> 4) * 16) ^ ((r & 7) << 4);
        if constexpr (MODE == 1) b0[nf] = *(const f16x8*)(smem + 16384 + bo);
        b1[nf] = *(const f16x8*)(smem + 32768 + bo);
      }
#pragma unroll
      for (int mf = 0; mf < 4; ++mf)
#pragma unroll
        for (int nf = 0; nf < 2; ++nf) {
          if constexpr (MODE == 1) {
            accB[mf][nf] = MFMA16(a0[mf], b0[nf], accB[mf][nf]);
            accR[mf][nf] = MFMA16(a1[mf], b1[nf], accR[mf][nf]);
          } else {
            accR[mf][nf] = MFMA16(a0[mf], b1[nf], accR[mf][nf]);
          }
        }
    }
    __syncthreads();
  }
#pragma unroll
  for (int mf = 0; mf < 4; ++mf)
#pragma unroll
    for (int nf = 0; nf < 2; ++nf) {
      int col = bn * 128 + wn * 32 + nf * 16 + (lane & 15);
      int row0 = bm * 64 + mf * 16 + ((lane >> 4) << 2);
#pragma unroll
      for (int rr = 0; rr < 4; ++rr) {
        size_t o = (size_t)(row0 + rr) * HIDC + col;
        if constexpr (MODE == 1) Zb[o] = accB[mf][nf][rr];
        Zr[o] = accR[mf][nf][rr];
      }
    }
}

__global__ __launch_bounds__(256) void k_stats(const float* __restrict__ Z,
                                               const float* __restrict__ Zlo,
                                               const float* __restrict__ msk,
                                               const float* __restrict__ bias,
                                               int dodrop,
                                               double* __restrict__ m_out,
                                               double* __restrict__ r_out) {
  __shared__ double sm[4][64];
  __shared__ double sq[4][64];
  const int li = threadIdx.x & 63, rg = threadIdx.x >> 6;
  const int c = blockIdx.x * 64 + li;
  const double bb = dodrop ? (double)bias[c] : 0.0;
  double s = 0.0, s2 = 0.0;
  for (int r = rg; r < BATCH; r += 4) {
    size_t i = (size_t)r * HIDC + c;
    double v = (double)Z[i];
    if (Zlo) v += (double)Zlo[i];
    if (dodrop) v = (msk[i] >= 0.5f) ? 2.0 * (v + bb) : 0.0;
    s += v;
    s2 += v * v;
  }
  sm[rg][li] = s;
  sq[rg][li] = s2;
  __syncthreads();
  if (rg == 0) {
    double S = sm[0][li] + sm[1][li] + sm[2][li] + sm[3][li];
    double S2 = sq[0][li] + sq[1][li] + sq[2][li] + sq[3][li];
    double m = S / 512.0;
    double var = S2 / 512.0 - m * m;
    m_out[c] = m;
    r_out[c] = 1.0 / sqrt(var + 1e-5);
  }
}

__global__ __launch_bounds__(256) void k_bn(float* __restrict__ Z,
                                            const float* __restrict__ Zlo,
                                            const double* __restrict__ m_arr,
                                            const double* __restrict__ r_arr,
                                            const float* __restrict__ g,
                                            const float* __restrict__ be,
                                            _Float16* __restrict__ aux, int auxmode,
                                            const float* __restrict__ msk,
                                            const float* __restrict__ bias, int dodrop) {
  int idx = blockIdx.x * 256 + threadIdx.x;
  int row = idx / 1536;
  int c4 = (idx - row * 1536) * 4;
  size_t base = (size_t)row * HIDC + c4;
  float4 z = *(const float4*)(Z + base);
  float zz[4] = {z.x, z.y, z.z, z.w};
  float zl[4] = {0.f, 0.f, 0.f, 0.f};
  if (Zlo) {
    float4 t4 = *(const float4*)(Zlo + base);
    zl[0] = t4.x; zl[1] = t4.y; zl[2] = t4.z; zl[3] = t4.w;
  }
  float mk[4] = {1.f, 1.f, 1.f, 1.f};
  if (dodrop) {
    float4 t4 = *(const float4*)(msk + base);
    mk[0] = t4.x; mk[1] = t4.y; mk[2] = t4.z; mk[3] = t4.w;
  }
  float o[4];
  f16x4 a4;
#pragma unroll
  for (int e = 0; e < 4; ++e) {
    int c = c4 + e;
    double v = (double)zz[e] + (double)zl[e];
    if (dodrop) v = (mk[e] >= 0.5f) ? 2.0 * (v + (double)bias[c]) : 0.0;
    double bnv = (double)g[c] * ((v - m_arr[c]) * r_arr[c]) + (double)be[c];
    bnv = bnv > 1.0 ? 1.0 : (bnv < -1.0 ? -1.0 : bnv);
    o[e] = (float)bnv;
    if (auxmode == 0)
      a4[e] = bnv > 0.0 ? (_Float16)1.0f : (bnv < 0.0 ? (_Float16)(-1.0f) : (_Float16)0.0f);
    else
      a4[e] = (_Float16)o[e];
  }
  float4 ov = {o[0], o[1], o[2], o[3]};
  *(float4*)(Z + base) = ov;
  if (auxmode < 2) *(f16x4*)(aux + base) = a4;
}

// ===========================================================================
extern "C" void kernel_launch(void* const* d_in, const int* in_sizes, int n_in,
                              void* d_out, int out_size, void* d_ws, size_t ws_size,
                              hipStream_t stream) {
  const float* x   = (const float*)d_in[0];
  const float* mkb = (const float*)d_in[1];
  const float* mkr = (const float*)d_in[2];
  const float* w1  = (const float*)d_in[3];
  const float* w2  = (const float*)d_in[5];
  const float* w3  = (const float*)d_in[7];
  const float* b3  = (const float*)d_in[8];
  const float* w4  = (const float*)d_in[9];
  const float* b4  = (const float*)d_in[10];
  const float* g1  = (const float*)d_in[11]; const float* be1 = (const float*)d_in[12];
  const float* g2  = (const float*)d_in[13]; const float* be2 = (const float*)d_in[14];
  const float* g3  = (const float*)d_in[15]; const float* be3 = (const float*)d_in[16];

  float* outp = (float*)d_out;
  float* logp = outp;
  float* outo = outp + 5120;
  float* B1 = outp + 10240;
  float* R1 = outp + 3155968;
  float* B2 = outp + 6301696;
  float* R2 = outp + 9447424;
  float* B3 = outp + 12593152;
  float* R3 = outp + 15738880;

  char* ws = (char*)d_ws;
  _Float16* xh  = (_Float16*)(ws + OFF_XH);
  float* z1lo   = (float*)(ws + OFF_Z1LO);
  _Float16* sB  = (_Float16*)(ws + OFF_SB);
  _Float16* rF  = (_Float16*)(ws + OFF_RF);
  double* stats = (double*)(ws + OFF_STATS);

  if (ws_size >= WS_NEED) {
    double* ppart = (double*)(ws + OFF_PPART);
    float* zpb    = (float*)(ws + OFF_ZPB);
    float* zpr    = (float*)(ws + OFF_ZPR);
    _Float16* w1v = (_Float16*)(ws + OFF_W1V);
    _Float16* wv  = (_Float16*)(ws + OFF_WV);
    _Float16* wsg = (_Float16*)(ws + OFF_WS2);
    // layer-1-phase aliases (regions free until conv_w23 runs)
    char* a8 = (char*)(ws + OFF_WS2);                       // 4 digit planes
    char* s1 = (char*)(ws + OFF_WS2 + 2097152ull);          // sign(w1) i8
    int* D0 = (int*)(ws + OFF_ZPB);
    int* D1 = (int*)(ws + OFF_ZPR);
    int* D2 = (int*)(ws + OFF_WV);
    int* D3 = (int*)(ws + OFF_WV + 12582912ull);

    // ---- layer 1 ----
    k_prep_x<<<416, 256, 0, stream>>>(x, xh);
    k_conv_w1<<<2496, 256, 0, stream>>>(w1, w1v);
    k_quant_x<<<1664, 256, 0, stream>>>(x, a8);
    k_sign_w1<<<19968, 256, 0, stream>>>(w1, s1);
    k_gemm_i8<<<dim3(48, 4, 4), 256, 0, stream>>>(a8, s1, D0, D1, D2, D3);
    k_combine1<<<3072, 256, 0, stream>>>(D0, D1, D2, D3, B1, z1lo);
    {
      Gemm4 P{};
      P.j[0] = {xh, w1v, R1, 832, 0, 13};
      P.j[1] = P.j[0]; P.j[2] = P.j[0]; P.j[3] = P.j[0];
      k_gemm16<<<dim3(48, 4, 1), 256, 0, stream>>>(P);
    }
    {
      St2 S{}; S.j[0] = {B1, z1lo, nullptr}; S.j[1] = {R1, nullptr, nullptr};
      S.bias = nullptr; S.dodrop = 0; S.ppart = ppart;
      k_stats_part<<<dim3(96, 8, 2), 256, 0, stream>>>(S);
      k_stats_fin<<<dim3(24, 1, 2), 256, 0, stream>>>(ppart, stats);
      Bn2 B{}; B.j[0] = {B1, z1lo, sB, nullptr, 0}; B.j[1] = {R1, nullptr, rF, nullptr, 1};
      B.stats = stats; B.g = g1; B.be = be1; B.bias = nullptr; B.dodrop = 0;
      k_bn2<<<dim3(3072, 1, 2), 256, 0, stream>>>(B);
    }
    // ---- layer 2 ----
    k_conv_w23<<<18432, 256, 0, stream>>>(w2, wv, wsg);
    {
      Gemm4 P{};
      P.j[0] = {sB, wsg, B2, HIDC, 0, 48};
      P.j[1] = {sB, wsg, zpb, HIDC, 3072, 48};
      P.j[2] = {rF, wv, R2, HIDC, 0, 48};
      P.j[3] = {rF, wv, zpr, HIDC, 3072, 48};
      k_gemm16<<<dim3(48, 4, 4), 256, 0, stream>>>(P);
    }
    {
      St2 S{}; S.j[0] = {B2, zpb, nullptr}; S.j[1] = {R2, zpr, nullptr};
      S.bias = nullptr; S.dodrop = 0; S.ppart = ppart;
      k_stats_part<<<dim3(96, 8, 2), 256, 0, stream>>>(S);
      k_stats_fin<<<dim3(24, 1, 2), 256, 0, stream>>>(ppart, stats);
      Bn2 B{}; B.j[0] = {B2, zpb, sB, nullptr, 0}; B.j[1] = {R2, zpr, rF, nullptr, 1};
      B.stats = stats; B.g = g2; B.be = be2; B.bias = nullptr; B.dodrop = 0;
      k_bn2<<<dim3(3072, 1, 2), 256, 0, stream>>>(B);
    }
    // ---- layer 3 ----
    k_conv_w23<<<18432, 256, 0, stream>>>(w3, wv, wsg);
    {
      Gemm4 P{};
      P.j[0] = {sB, wsg, B3, HIDC, 0, 48};
      P.j[1] = {sB, wsg, zpb, HIDC, 3072, 48};
      P.j[2] = {rF, wv, R3, HIDC, 0, 48};
      P.j[3] = {rF, wv, zpr, HIDC, 3072, 48};
      k_gemm16<<<dim3(48, 4, 4), 256, 0, stream>>>(P);
    }
    {
      St2 S{}; S.j[0] = {B3, zpb, mkb}; S.j[1] = {R3, zpr, mkr};
      S.bias = b3; S.dodrop = 1; S.ppart = ppart;
      k_stats_part<<<dim3(96, 8, 2), 256, 0, stream>>>(S);
      k_stats_fin<<<dim3(24, 1, 2), 256, 0, stream>>>(ppart, stats);
      Bn2 B{}; B.j[0] = {B3, zpb, nullptr, mkb, 2}; B.j[1] = {R3, zpr, nullptr, mkr, 2};
      B.stats = stats; B.g = g3; B.be = be3; B.bias = b3; B.dodrop = 1;
      k_bn2<<<dim3(3072, 1, 2), 256, 0, stream>>>(B);
    }
    k_head<<<512, 256, 0, stream>>>(B3, w4, b4, outo, logp);
  } else {
    // ---------- round-1 fallback ----------
    double* m_b = stats; double* r_b = stats + 6144;
    double* m_r = stats + 12288; double* r_r = stats + 18432;
    k_prep_x<<<416, 256, 0, stream>>>(x, xh);
    k_gemm64<<<dim3(96, 8), 256, 0, stream>>>(x, w1, B1, z1lo);
    k_gemm<0><<<dim3(48, 8), 256, 0, stream>>>(xh, nullptr, w1, nullptr, R1, 832, 784, 13);
    k_stats<<<96, 256, 0, stream>>>(B1, z1lo, nullptr, nullptr, 0, m_b, r_b);
    k_stats<<<96, 256, 0, stream>>>(R1, nullptr, nullptr, nullptr, 0, m_r, r_r);
    k_bn<<<3072, 256, 0, stream>>>(B1, z1lo, m_b, r_b, g1, be1, sB, 0, nullptr, nullptr, 0);
    k_bn<<<3072, 256, 0, stream>>>(R1, nullptr, m_r, r_r, g1, be1, rF, 1, nullptr, nullptr, 0);
    k_gemm<1><<<dim3(48, 8), 256, 0, stream>>>(sB, rF, w2, B2, R2, 6144, 6144, 96);
    k_stats<<<96, 256, 0, stream>>>(B2, nullptr, nullptr, nullptr, 0, m_b, r_b);
    k_stats<<<96, 256, 0, stream>>>(R2, nullptr, nullptr, nullptr, 0, m_r, r_r);
    k_bn<<<3072, 256, 0, stream>>>(B2, nullptr, m_b, r_b, g2, be2, sB, 0, nullptr, nullptr, 0);
    k_bn<<<3072, 256, 0, stream>>>(R2, nullptr, m_r, r_r, g2, be2, rF, 1, nullptr, nullptr, 0);
    k_gemm<1><<<dim3(48, 8), 256, 0, stream>>>(sB, rF, w3, B3, R3, 6144, 6144, 96);
    k_stats<<<96, 256, 0, stream>>>(B3, nullptr, mkb, b3, 1, m_b, r_b);
    k_stats<<<96, 256, 0, stream>>>(R3, nullptr, mkr, b3, 1, m_r, r_r);
    k_bn<<<3072, 256, 0, stream>>>(B3, nullptr, m_b, r_b, g3, be3, nullptr, 2, mkb, b3, 1);
    k_bn<<<3072, 256, 0, stream>>>(R3, nullptr, m_r, r_r, g3, be3, nullptr, 2, mkr, b3, 1);
    k_head<<<512, 256, 0, stream>>>(B3, w4, b4, outo, logp);
  }
}

// Round 6
// 564.077 us; speedup vs baseline: 3.1707x; 1.1876x over previous
//
#include <hip/hip_runtime.h>

// Binarized MLP forward (512x784 -> 3x6144 -> 10), dual binary/real paths.
// Round 6: binary-path GEMMs (layers 2/3) moved to i8 MFMA (16x16x64, 2x f16
// rate, exact +-1 integer accum); mixed dispatch with real-path f16 jobs.
// wsg and sB stored as i8 (less HBM traffic). Layer-1 i8-digit stack unchanged
// (validated round 5).
//
// Precision plan:
//  - layer1 binary: exact i8-digit MFMA + fp64 combine, hi/lo fp32 storage
//  - layer2/3 binary: i8 MFMA K=64, EXACT (i32 sums <= 6144, fp32-exact)
//  - real path: fp16 MFMA (error ~1e-3 << 2% thresholds)
//  - all batch-norm stats and normalization in fp64

typedef _Float16 f16x8 __attribute__((ext_vector_type(8)));
typedef _Float16 f16x4 __attribute__((ext_vector_type(4)));
typedef float f32x4 __attribute__((ext_vector_type(4)));
typedef int i32x4 __attribute__((ext_vector_type(4)));

#define MFMA16(a, b, c) __builtin_amdgcn_mfma_f32_16x16x32_f16((a), (b), (c), 0, 0, 0)
#define MFMAI8K32(a, b, c) __builtin_amdgcn_mfma_i32_16x16x32_i8((a), (b), (c), 0, 0, 0)
#define MFMAI8K64(a, b, c) __builtin_amdgcn_mfma_i32_16x16x64_i8((a), (b), (c), 0, 0, 0)

#define HIDC 6144
#define BATCH 512

// ---- workspace layout (bytes) ----
#define OFF_XH    0ull          // 512x832 fp16                    851,968
#define OFF_Z1LO  851968ull     // 512x6144 fp32                12,582,912
#define OFF_SB8   13434880ull   // 512x6144 i8 sign acts         3,145,728
#define OFF_RF    16580608ull   // 512x6144 fp16 real acts       6,291,456
#define OFF_STATS 22872064ull   // 4x6144 fp64                     196,608
#define OFF_PPART 23068672ull   // 2x8x2x6144 fp64               1,572,864
#define OFF_ZPB   24641536ull   // 512x6144 fp32 splitK bin     12,582,912
#define OFF_ZPR   37224448ull   // 512x6144 fp32 splitK real    12,582,912
#define OFF_W1V   49807360ull   // 6144x832 fp16                10,223,616
#define OFF_WV    60030976ull   // 6144x6144 fp16               75,497,472
#define OFF_WS8   135528448ull  // 6144x6144 i8 sign weights    37,748,736
#define WS_NEED   173277184ull

// layer-1 scratch carved from regions free during layer 1:
#define A8_STRIDE 425984ull     // 512*832 bytes per digit plane

// ---------------------------------------------------------------------------
__device__ __forceinline__ void load_lds16(const void* g, char* lds) {
  __builtin_amdgcn_global_load_lds((const __attribute__((address_space(1))) void*)g,
                                   (__attribute__((address_space(3))) void*)lds, 16, 0, 0);
}

// ---------------------------------------------------------------------------
// x (512x784 fp32) -> xh (512x832 fp16, zero-padded cols 784..831)
__global__ __launch_bounds__(256) void k_prep_x(const float* __restrict__ x,
                                                _Float16* __restrict__ xh) {
  int idx = blockIdx.x * 256 + threadIdx.x;  // over 512*208 float4 positions
  if (idx >= 512 * 208) return;
  int row = idx / 208, c4 = idx - row * 208;
  f16x4 h;
  if (c4 < 196) {
    float4 v = *(const float4*)(x + (size_t)row * 784 + c4 * 4);
    h[0] = (_Float16)v.x; h[1] = (_Float16)v.y; h[2] = (_Float16)v.z; h[3] = (_Float16)v.w;
  } else {
    h[0] = (_Float16)0.f; h[1] = (_Float16)0.f; h[2] = (_Float16)0.f; h[3] = (_Float16)0.f;
  }
  *(f16x4*)(xh + (size_t)row * 832 + c4 * 4) = h;
}

// ---------------------------------------------------------------------------
// x -> 4 signed base-256 digit planes of rint(x*2^24), each [512][832] i8.
__global__ __launch_bounds__(256) void k_quant_x(const float* __restrict__ x,
                                                 char* __restrict__ a8) {
  int idx = blockIdx.x * 256 + threadIdx.x;  // 512*832 = 425984
  if (idx >= 512 * 832) return;
  int row = idx / 832, k = idx - row * 832;
  float v = (k < 784) ? x[(size_t)row * 784 + k] : 0.f;
  int q = (int)lrintf(v * 16777216.0f);
  int d0 = ((q + 128) & 255) - 128; q = (q - d0) >> 8;
  int d1 = ((q + 128) & 255) - 128; q = (q - d1) >> 8;
  int d2 = ((q + 128) & 255) - 128; q = (q - d2) >> 8;
  a8[idx] = (char)d0;
  a8[A8_STRIDE + idx] = (char)d1;
  a8[2 * A8_STRIDE + idx] = (char)d2;
  a8[3 * A8_STRIDE + idx] = (char)q;  // |q| <= 9
}

// ---------------------------------------------------------------------------
// w1 (6144x784 fp32) -> s1 (6144x832 i8 sign, zero-padded)
__global__ __launch_bounds__(256) void k_sign_w1(const float* __restrict__ w,
                                                 char* __restrict__ s1) {
  int idx = blockIdx.x * 256 + threadIdx.x;  // 6144*832
  if (idx >= 6144 * 832) return;
  int r = idx / 832, k = idx - r * 832;
  char s = 0;
  if (k < 784) {
    float v = w[(size_t)r * 784 + k];
    s = v > 0.f ? 1 : (v < 0.f ? -1 : 0);
  }
  s1[idx] = s;
}

// ---------------------------------------------------------------------------
// w1 (6144x784 fp32) -> W1v (6144x832 fp16, zero-padded) [real path]
__global__ __launch_bounds__(256) void k_conv_w1(const float* __restrict__ w,
                                                 _Float16* __restrict__ wv) {
  int idx = blockIdx.x * 256 + threadIdx.x;  // 6144*104 f16x8 groups
  if (idx >= 6144 * 104) return;
  int r = idx / 104, c8 = idx - r * 104;
  f16x8 hv;
  if (c8 < 98) {
    const float* s = w + (size_t)r * 784 + c8 * 8;
    float4 v0 = *(const float4*)s;
    float4 v1 = *(const float4*)(s + 4);
    float a[8] = {v0.x, v0.y, v0.z, v0.w, v1.x, v1.y, v1.z, v1.w};
#pragma unroll
    for (int e = 0; e < 8; ++e) hv[e] = (_Float16)a[e];
  } else {
#pragma unroll
    for (int e = 0; e < 8; ++e) hv[e] = (_Float16)0.f;
  }
  *(f16x8*)(wv + (size_t)r * 832 + c8 * 8) = hv;
}

// ---------------------------------------------------------------------------
// w (6144x6144 fp32) -> Wv (fp16 value), Ws8 (i8 sign)
__global__ __launch_bounds__(256) void k_conv_w23(const float* __restrict__ w,
                                                  _Float16* __restrict__ wv,
                                                  char* __restrict__ ws8) {
  int idx = blockIdx.x * 256 + threadIdx.x;  // 6144*768 groups of 8
  size_t o8 = (size_t)idx * 8;
  const float* s = w + o8;
  float4 v0 = *(const float4*)s;
  float4 v1 = *(const float4*)(s + 4);
  float a[8] = {v0.x, v0.y, v0.z, v0.w, v1.x, v1.y, v1.z, v1.w};
  f16x8 hv;
  unsigned long long sbits = 0;
#pragma unroll
  for (int e = 0; e < 8; ++e) {
    hv[e] = (_Float16)a[e];
    char sg = a[e] > 0.f ? 1 : (a[e] < 0.f ? -1 : 0);
    sbits |= ((unsigned long long)(unsigned char)sg) << (8 * e);
  }
  *(f16x8*)(wv + o8) = hv;
  *(unsigned long long*)(ws8 + o8) = sbits;
}

// ---------------------------------------------------------------------------
// Layer-1 digit i8 GEMM: D_z[512x6144] (i32) = digit_z(x) @ s1^T.  K=832.
__global__ __launch_bounds__(256) void k_gemm_i8(const char* __restrict__ a8,
                                                 const char* __restrict__ s1,
                                                 int* __restrict__ D0,
                                                 int* __restrict__ D1,
                                                 int* __restrict__ D2,
                                                 int* __restrict__ D3) {
  __shared__ __align__(16) char smem[16384];  // A @0 (8K), B @8192 (8K)
  const int z = blockIdx.z;
  const char* A = a8 + (size_t)z * A8_STRIDE;
  int* C = D0;
  if (z == 1) C = D1;
  if (z == 2) C = D2;
  if (z == 3) C = D3;
  const int t = threadIdx.x;
  const int lane = t & 63, wid = t >> 6;
  const int wm = wid >> 1, wn = wid & 1;
  const int bn = blockIdx.x, bm = blockIdx.y;

  i32x4 acc[4][4];
#pragma unroll
  for (int mf = 0; mf < 4; ++mf)
#pragma unroll
    for (int nf = 0; nf < 4; ++nf) acc[mf][nf] = (i32x4){0, 0, 0, 0};

  for (int kt = 0; kt < 13; ++kt) {
    const int k0 = kt * 64;
#pragma unroll
    for (int i = 0; i < 2; ++i) {
      int p = i * 256 + t;
      int r = p >> 2, c16 = p & 3;
      load_lds16(A + (size_t)(bm * 128 + r) * 832 + k0 + c16 * 16, smem + p * 16);
    }
#pragma unroll
    for (int i = 0; i < 2; ++i) {
      int p = i * 256 + t;
      int r = p >> 2, c16 = p & 3;
      load_lds16(s1 + (size_t)(bn * 128 + r) * 832 + k0 + c16 * 16, smem + 8192 + p * 16);
    }
    __syncthreads();
#pragma unroll
    for (int kk = 0; kk < 2; ++kk) {  // two K=32 halves of BK=64
      long av[4], bv[4];
#pragma unroll
      for (int mf = 0; mf < 4; ++mf) {
        int r = wm * 64 + mf * 16 + (lane & 15);
        av[mf] = *(const long*)(smem + r * 64 + kk * 32 + (lane >> 4) * 8);
      }
#pragma unroll
      for (int nf = 0; nf < 4; ++nf) {
        int r = wn * 64 + nf * 16 + (lane & 15);
        bv[nf] = *(const long*)(smem + 8192 + r * 64 + kk * 32 + (lane >> 4) * 8);
      }
#pragma unroll
      for (int mf = 0; mf < 4; ++mf)
#pragma unroll
        for (int nf = 0; nf < 4; ++nf) acc[mf][nf] = MFMAI8K32(av[mf], bv[nf], acc[mf][nf]);
    }
    __syncthreads();
  }
#pragma unroll
  for (int mf = 0; mf < 4; ++mf)
#pragma unroll
    for (int nf = 0; nf < 4; ++nf) {
      int col = bn * 128 + wn * 64 + nf * 16 + (lane & 15);
      int row0 = bm * 128 + wm * 64 + mf * 16 + ((lane >> 4) << 2);
#pragma unroll
      for (int rr = 0; rr < 4; ++rr) {
        C[(size_t)(row0 + rr) * HIDC + col] = acc[mf][nf][rr];
      }
    }
}

// ---------------------------------------------------------------------------
// Combine digit GEMMs: Z = (((D3*256+D2)*256+D1)*256+D0) * 2^-24, hi/lo fp32.
__global__ __launch_bounds__(256) void k_combine1(const int* __restrict__ D0,
                                                  const int* __restrict__ D1,
                                                  const int* __restrict__ D2,
                                                  const int* __restrict__ D3,
                                                  float* __restrict__ Zhi,
                                                  float* __restrict__ Zlo) {
  size_t i4 = ((size_t)blockIdx.x * 256 + threadIdx.x) * 4;  // 512*6144 elems
  i32x4 v0 = *(const i32x4*)(D0 + i4);
  i32x4 v1 = *(const i32x4*)(D1 + i4);
  i32x4 v2 = *(const i32x4*)(D2 + i4);
  i32x4 v3 = *(const i32x4*)(D3 + i4);
  float4 hi, lo;
  float* hp = &hi.x;
  float* lp = &lo.x;
#pragma unroll
  for (int e = 0; e < 4; ++e) {
    double zv = (((double)v3[e] * 256.0 + (double)v2[e]) * 256.0 + (double)v1[e]) * 256.0 +
                (double)v0[e];
    zv *= (1.0 / 16777216.0);
    float h = (float)zv;
    hp[e] = h;
    lp[e] = (float)(zv - (double)h);
  }
  *(float4*)(Zhi + i4) = hi;
  *(float4*)(Zlo + i4) = lo;
}

// ---------------------------------------------------------------------------
// Mixed GEMM dispatch: per blockIdx.z job, either
//   is8=1: i8 path, BK=128: C = A8[512xK] @ B8[6144xK]^T  (sign binary, exact)
//   is8=0: f16 path, BK=64: C = A[512xK] @ B[6144xK]^T
// BM=BN=128, 4 waves (2x2), global_load_lds, m97 2-barrier loop.
struct MixJob {
  const void* A;
  const void* B;
  float* C;
  int K;
  int kstart;
  int ksteps;
  int is8;
};
struct Mix4 { MixJob j[4]; };

__global__ __launch_bounds__(256) void k_gemm_mix(Mix4 P) {
  __shared__ __align__(16) char smem[32768];  // A @0 (16K), B @16384 (16K)
  MixJob J = P.j[0];
  if (blockIdx.z == 1) J = P.j[1];
  if (blockIdx.z == 2) J = P.j[2];
  if (blockIdx.z == 3) J = P.j[3];
  const int t = threadIdx.x;
  const int lane = t & 63, wid = t >> 6;
  const int wm = wid >> 1, wn = wid & 1;
  const int bn = blockIdx.x, bm = blockIdx.y;
  const size_t K = (size_t)J.K;

  if (J.is8) {
    // ---------------- i8 binary path (BK=128) ----------------
    const char* A = (const char*)J.A;
    const char* B = (const char*)J.B;
    i32x4 acc[4][4];
#pragma unroll
    for (int mf = 0; mf < 4; ++mf)
#pragma unroll
      for (int nf = 0; nf < 4; ++nf) acc[mf][nf] = (i32x4){0, 0, 0, 0};

    for (int kt = 0; kt < J.ksteps; ++kt) {
      const int k0 = J.kstart + kt * 128;
#pragma unroll
      for (int i = 0; i < 4; ++i) {
        int p = i * 256 + t;
        int r = p >> 3, c16 = p & 7;
        load_lds16(A + (size_t)(bm * 128 + r) * K + k0 + c16 * 16, smem + p * 16);
      }
#pragma unroll
      for (int i = 0; i < 4; ++i) {
        int p = i * 256 + t;
        int r = p >> 3, c16 = p & 7;
        load_lds16(B + (size_t)(bn * 128 + r) * K + k0 + c16 * 16, smem + 16384 + p * 16);
      }
      __syncthreads();
#pragma unroll
      for (int kk = 0; kk < 2; ++kk) {  // two K=64 halves of BK=128
        i32x4 av[4], bv[4];
#pragma unroll
        for (int mf = 0; mf < 4; ++mf) {
          int r = wm * 64 + mf * 16 + (lane & 15);
          av[mf] = *(const i32x4*)(smem + r * 128 + kk * 64 + (lane >> 4) * 16);
        }
#pragma unroll
        for (int nf = 0; nf < 4; ++nf) {
          int r = wn * 64 + nf * 16 + (lane & 15);
          bv[nf] = *(const i32x4*)(smem + 16384 + r * 128 + kk * 64 + (lane >> 4) * 16);
        }
#pragma unroll
        for (int mf = 0; mf < 4; ++mf)
#pragma unroll
          for (int nf = 0; nf < 4; ++nf) acc[mf][nf] = MFMAI8K64(av[mf], bv[nf], acc[mf][nf]);
      }
      __syncthreads();
    }
#pragma unroll
    for (int mf = 0; mf < 4; ++mf)
#pragma unroll
      for (int nf = 0; nf < 4; ++nf) {
        int col = bn * 128 + wn * 64 + nf * 16 + (lane & 15);
        int row0 = bm * 128 + wm * 64 + mf * 16 + ((lane >> 4) << 2);
#pragma unroll
        for (int rr = 0; rr < 4; ++rr) {
          J.C[(size_t)(row0 + rr) * HIDC + col] = (float)acc[mf][nf][rr];  // exact (<2^24)
        }
      }
  } else {
    // ---------------- f16 real path (BK=64) ----------------
    const _Float16* A = (const _Float16*)J.A;
    const _Float16* B = (const _Float16*)J.B;
    f32x4 acc[4][4];
#pragma unroll
    for (int mf = 0; mf < 4; ++mf)
#pragma unroll
      for (int nf = 0; nf < 4; ++nf) acc[mf][nf] = (f32x4){0.f, 0.f, 0.f, 0.f};

    for (int kt = 0; kt < J.ksteps; ++kt) {
      const int k0 = J.kstart + kt * 64;
#pragma unroll
      for (int i = 0; i < 4; ++i) {
        int p = i * 256 + t;
        int r = p >> 3, c16 = p & 7;
        load_lds16(A + (size_t)(bm * 128 + r) * K + k0 + c16 * 8, smem + p * 16);
      }
#pragma unroll
      for (int i = 0; i < 4; ++i) {
        int p = i * 256 + t;
        int r = p >> 3, c16 = p & 7;
        load_lds16(B + (size_t)(bn * 128 + r) * K + k0 + c16 * 8, smem + 16384 + p * 16);
      }
      __syncthreads();
#pragma unroll
      for (int kk = 0; kk < 2; ++kk) {
        f16x8 av[4], bv[4];
#pragma unroll
        for (int mf = 0; mf < 4; ++mf) {
          int r = wm * 64 + mf * 16 + (lane & 15);
          av[mf] = *(const f16x8*)(smem + r * 128 + kk * 64 + (lane >> 4) * 16);
        }
#pragma unroll
        for (int nf = 0; nf < 4; ++nf) {
          int r = wn * 64 + nf * 16 + (lane & 15);
          bv[nf] = *(const f16x8*)(smem + 16384 + r * 128 + kk * 64 + (lane >> 4) * 16);
        }
#pragma unroll
        for (int mf = 0; mf < 4; ++mf)
#pragma unroll
          for (int nf = 0; nf < 4; ++nf) acc[mf][nf] = MFMA16(av[mf], bv[nf], acc[mf][nf]);
      }
      __syncthreads();
    }
#pragma unroll
    for (int mf = 0; mf < 4; ++mf)
#pragma unroll
      for (int nf = 0; nf < 4; ++nf) {
        int col = bn * 128 + wn * 64 + nf * 16 + (lane & 15);
        int row0 = bm * 128 + wm * 64 + mf * 16 + ((lane >> 4) << 2);
#pragma unroll
        for (int rr = 0; rr < 4; ++rr) {
          J.C[(size_t)(row0 + rr) * HIDC + col] = acc[mf][nf][rr];
        }
      }
  }
}

// ---------------------------------------------------------------------------
// Two-stage per-column stats (mean, rstd over 512 rows), fp64.
struct StJob { const float* Z; const float* Zpart; const float* msk; };
struct St2 { StJob j[2]; const float* bias; int dodrop; double* ppart; };

__global__ __launch_bounds__(256) void k_stats_part(St2 P) {
  __shared__ double sm[4][64];
  __shared__ double sq[4][64];
  const int z = blockIdx.z;
  StJob J = z ? P.j[1] : P.j[0];
  const int li = threadIdx.x & 63, rg = threadIdx.x >> 6;
  const int col = blockIdx.x * 64 + li;
  const double bb = P.dodrop ? (double)P.bias[col] : 0.0;
  double s = 0.0, s2 = 0.0;
#pragma unroll 4
  for (int rr = 0; rr < 16; ++rr) {
    int r = blockIdx.y * 64 + rg * 16 + rr;
    size_t i = (size_t)r * HIDC + col;
    double v = (double)J.Z[i];
    if (J.Zpart) v += (double)J.Zpart[i];
    if (P.dodrop) v = (J.msk[i] >= 0.5f) ? 2.0 * (v + bb) : 0.0;
    s += v;
    s2 += v * v;
  }
  sm[rg][li] = s;
  sq[rg][li] = s2;
  __syncthreads();
  if (rg == 0) {
    double S = sm[0][li] + sm[1][li] + sm[2][li] + sm[3][li];
    double S2 = sq[0][li] + sq[1][li] + sq[2][li] + sq[3][li];
    size_t o = ((size_t)(z * 8 + blockIdx.y) * 2) * HIDC + col;
    P.ppart[o] = S;
    P.ppart[o + HIDC] = S2;
  }
}

__global__ __launch_bounds__(256) void k_stats_fin(const double* __restrict__ ppart,
                                                   double* __restrict__ stats) {
  const int z = blockIdx.z;
  const int c = blockIdx.x * 256 + threadIdx.x;
  double S = 0.0, S2 = 0.0;
#pragma unroll
  for (int y = 0; y < 8; ++y) {
    size_t o = ((size_t)(z * 8 + y) * 2) * HIDC + c;
    S += ppart[o];
    S2 += ppart[o + HIDC];
  }
  double m = S / 512.0;
  double var = S2 / 512.0 - m * m;
  stats[z * 2 * HIDC + c] = m;
  stats[z * 2 * HIDC + HIDC + c] = 1.0 / sqrt(var + 1e-5);
}

// ---------------------------------------------------------------------------
// BN (+optional dropout) + hardtanh, fp64 math; dual-path via grid.z.
// auxmode: 0 -> aux (i8) = sign(out) ; 1 -> aux (f16) = out ; 2 -> none.
struct BnJob { float* Z; const float* Zpart; void* aux; const float* msk; int auxmode; };
struct Bn2 {
  BnJob j[2];
  const double* stats;
  const float* g; const float* be; const float* bias;
  int dodrop;
};

__global__ __launch_bounds__(256) void k_bn2(Bn2 P) {
  const int z = blockIdx.z;
  BnJob J = z ? P.j[1] : P.j[0];
  const double* m_arr = P.stats + (size_t)z * 2 * HIDC;
  const double* r_arr = m_arr + HIDC;
  int idx = blockIdx.x * 256 + threadIdx.x;  // 512*1536 float4 positions
  int row = idx / 1536;
  int c4 = (idx - row * 1536) * 4;
  size_t base = (size_t)row * HIDC + c4;
  float4 zv = *(const float4*)(J.Z + base);
  float zz[4] = {zv.x, zv.y, zv.z, zv.w};
  float zl[4] = {0.f, 0.f, 0.f, 0.f};
  if (J.Zpart) {
    float4 t4 = *(const float4*)(J.Zpart + base);
    zl[0] = t4.x; zl[1] = t4.y; zl[2] = t4.z; zl[3] = t4.w;
  }
  float mk[4] = {1.f, 1.f, 1.f, 1.f};
  if (P.dodrop) {
    float4 t4 = *(const float4*)(J.msk + base);
    mk[0] = t4.x; mk[1] = t4.y; mk[2] = t4.z; mk[3] = t4.w;
  }
  float o[4];
  f16x4 a4;
  int sbits = 0;
#pragma unroll
  for (int e = 0; e < 4; ++e) {
    int c = c4 + e;
    double v = (double)zz[e] + (double)zl[e];
    if (P.dodrop) v = (mk[e] >= 0.5f) ? 2.0 * (v + (double)P.bias[c]) : 0.0;
    double bnv = (double)P.g[c] * ((v - m_arr[c]) * r_arr[c]) + (double)P.be[c];
    bnv = bnv > 1.0 ? 1.0 : (bnv < -1.0 ? -1.0 : bnv);
    o[e] = (float)bnv;
    char sg = bnv > 0.0 ? 1 : (bnv < 0.0 ? -1 : 0);
    sbits |= ((int)(unsigned char)sg) << (8 * e);
    a4[e] = (_Float16)o[e];
  }
  float4 ov = {o[0], o[1], o[2], o[3]};
  *(float4*)(J.Z + base) = ov;
  if (J.auxmode == 0) *(int*)((char*)J.aux + base) = sbits;
  if (J.auxmode == 1) *(f16x4*)((_Float16*)J.aux + base) = a4;
}

// ---------------------------------------------------------------------------
// Head: out = Bout3 @ w4^T + b4 (512x10, K=6144) + log_softmax, one block/row.
__global__ __launch_bounds__(256) void k_head(const float* __restrict__ B3,
                                              const float* __restrict__ w4,
                                              const float* __restrict__ b4,
                                              float* __restrict__ out,
                                              float* __restrict__ logp) {
  const int row = blockIdx.x, t = threadIdx.x;
  float acc[10];
#pragma unroll
  for (int j = 0; j < 10; ++j) acc[j] = 0.f;
  const float* a = B3 + (size_t)row * HIDC;
  for (int k4 = t; k4 < 1536; k4 += 256) {
    float4 av = *(const float4*)(a + k4 * 4);
#pragma unroll
    for (int j = 0; j < 10; ++j) {
      float4 wv = *(const float4*)(w4 + (size_t)j * HIDC + k4 * 4);
      acc[j] += av.x * wv.x + av.y * wv.y + av.z * wv.z + av.w * wv.w;
    }
  }
#pragma unroll
  for (int j = 0; j < 10; ++j)
    for (int off = 32; off; off >>= 1) acc[j] += __shfl_down(acc[j], off);
  __shared__ float sred[4][10];
  int wid = t >> 6, ln = t & 63;
  if (ln == 0)
#pragma unroll
    for (int j = 0; j < 10; ++j) sred[wid][j] = acc[j];
  __syncthreads();
  if (t == 0) {
    double o[10];
    double mx = -1e300;
#pragma unroll
    for (int j = 0; j < 10; ++j) {
      o[j] = (double)sred[0][j] + sred[1][j] + sred[2][j] + sred[3][j] + (double)b4[j];
      mx = o[j] > mx ? o[j] : mx;
    }
    double s = 0.0;
#pragma unroll
    for (int j = 0; j < 10; ++j) s += exp(o[j] - mx);
    double l = log(s) + mx;
#pragma unroll
    for (int j = 0; j < 10; ++j) {
      out[row * 10 + j] = (float)o[j];
      logp[row * 10 + j] = (float)(o[j] - l);
    }
  }
}

// ===========================================================================
extern "C" void kernel_launch(void* const* d_in, const int* in_sizes, int n_in,
                              void* d_out, int out_size, void* d_ws, size_t ws_size,
                              hipStream_t stream) {
  const float* x   = (const float*)d_in[0];
  const float* mkb = (const float*)d_in[1];
  const float* mkr = (const float*)d_in[2];
  const float* w1  = (const float*)d_in[3];
  const float* w2  = (const float*)d_in[5];
  const float* w3  = (const float*)d_in[7];
  const float* b3  = (const float*)d_in[8];
  const float* w4  = (const float*)d_in[9];
  const float* b4  = (const float*)d_in[10];
  const float* g1  = (const float*)d_in[11]; const float* be1 = (const float*)d_in[12];
  const float* g2  = (const float*)d_in[13]; const float* be2 = (const float*)d_in[14];
  const float* g3  = (const float*)d_in[15]; const float* be3 = (const float*)d_in[16];

  float* outp = (float*)d_out;
  float* logp = outp;
  float* outo = outp + 5120;
  float* B1 = outp + 10240;
  float* R1 = outp + 3155968;
  float* B2 = outp + 6301696;
  float* R2 = outp + 9447424;
  float* B3 = outp + 12593152;
  float* R3 = outp + 15738880;

  char* ws = (char*)d_ws;
  _Float16* xh  = (_Float16*)(ws + OFF_XH);
  float* z1lo   = (float*)(ws + OFF_Z1LO);
  char* sB8     = (char*)(ws + OFF_SB8);
  _Float16* rF  = (_Float16*)(ws + OFF_RF);
  double* stats = (double*)(ws + OFF_STATS);
  double* ppart = (double*)(ws + OFF_PPART);
  float* zpb    = (float*)(ws + OFF_ZPB);
  float* zpr    = (float*)(ws + OFF_ZPR);
  _Float16* w1v = (_Float16*)(ws + OFF_W1V);
  _Float16* wv  = (_Float16*)(ws + OFF_WV);
  char* ws8     = (char*)(ws + OFF_WS8);
  // layer-1-phase aliases (regions free until layer 2)
  char* a8 = (char*)(ws + OFF_WS8);                 // 4 digit planes (1.7 MB)
  char* s1 = (char*)(ws + OFF_WS8 + 2097152ull);    // sign(w1) i8 (5.1 MB)
  int* D0 = (int*)(ws + OFF_ZPB);
  int* D1 = (int*)(ws + OFF_ZPR);
  int* D2 = (int*)(ws + OFF_WV);
  int* D3 = (int*)(ws + OFF_WV + 12582912ull);

  // ---- layer 1 ----
  k_prep_x<<<416, 256, 0, stream>>>(x, xh);
  k_conv_w1<<<2496, 256, 0, stream>>>(w1, w1v);
  k_quant_x<<<1664, 256, 0, stream>>>(x, a8);
  k_sign_w1<<<19968, 256, 0, stream>>>(w1, s1);
  k_gemm_i8<<<dim3(48, 4, 4), 256, 0, stream>>>(a8, s1, D0, D1, D2, D3);
  k_combine1<<<3072, 256, 0, stream>>>(D0, D1, D2, D3, B1, z1lo);
  {
    Mix4 P{};
    P.j[0] = {xh, w1v, R1, 832, 0, 13, 0};
    P.j[1] = P.j[0]; P.j[2] = P.j[0]; P.j[3] = P.j[0];
    k_gemm_mix<<<dim3(48, 4, 1), 256, 0, stream>>>(P);
  }
  {
    St2 S{}; S.j[0] = {B1, z1lo, nullptr}; S.j[1] = {R1, nullptr, nullptr};
    S.bias = nullptr; S.dodrop = 0; S.ppart = ppart;
    k_stats_part<<<dim3(96, 8, 2), 256, 0, stream>>>(S);
    k_stats_fin<<<dim3(24, 1, 2), 256, 0, stream>>>(ppart, stats);
    Bn2 B{}; B.j[0] = {B1, z1lo, sB8, nullptr, 0}; B.j[1] = {R1, nullptr, rF, nullptr, 1};
    B.stats = stats; B.g = g1; B.be = be1; B.bias = nullptr; B.dodrop = 0;
    k_bn2<<<dim3(3072, 1, 2), 256, 0, stream>>>(B);
  }
  // ---- layer 2 ----
  k_conv_w23<<<18432, 256, 0, stream>>>(w2, wv, ws8);
  {
    Mix4 P{};
    P.j[0] = {sB8, ws8, B2, HIDC, 0, 24, 1};
    P.j[1] = {sB8, ws8, zpb, HIDC, 3072, 24, 1};
    P.j[2] = {rF, wv, R2, HIDC, 0, 48, 0};
    P.j[3] = {rF, wv, zpr, HIDC, 3072, 48, 0};
    k_gemm_mix<<<dim3(48, 4, 4), 256, 0, stream>>>(P);
  }
  {
    St2 S{}; S.j[0] = {B2, zpb, nullptr}; S.j[1] = {R2, zpr, nullptr};
    S.bias = nullptr; S.dodrop = 0; S.ppart = ppart;
    k_stats_part<<<dim3(96, 8, 2), 256, 0, stream>>>(S);
    k_stats_fin<<<dim3(24, 1, 2), 256, 0, stream>>>(ppart, stats);
    Bn2 B{}; B.j[0] = {B2, zpb, sB8, nullptr, 0}; B.j[1] = {R2, zpr, rF, nullptr, 1};
    B.stats = stats; B.g = g2; B.be = be2; B.bias = nullptr; B.dodrop = 0;
    k_bn2<<<dim3(3072, 1, 2), 256, 0, stream>>>(B);
  }
  // ---- layer 3 ----
  k_conv_w23<<<18432, 256, 0, stream>>>(w3, wv, ws8);
  {
    Mix4 P{};
    P.j[0] = {sB8, ws8, B3, HIDC, 0, 24, 1};
    P.j[1] = {sB8, ws8, zpb, HIDC, 3072, 24, 1};
    P.j[2] = {rF, wv, R3, HIDC, 0, 48, 0};
    P.j[3] = {rF, wv, zpr, HIDC, 3072, 48, 0};
    k_gemm_mix<<<dim3(48, 4, 4), 256, 0, stream>>>(P);
  }
  {
    St2 S{}; S.j[0] = {B3, zpb, mkb}; S.j[1] = {R3, zpr, mkr};
    S.bias = b3; S.dodrop = 1; S.ppart = ppart;
    k_stats_part<<<dim3(96, 8, 2), 256, 0, stream>>>(S);
    k_stats_fin<<<dim3(24, 1, 2), 256, 0, stream>>>(ppart, stats);
    Bn2 B{}; B.j[0] = {B3, zpb, nullptr, mkb, 2}; B.j[1] = {R3, zpr, nullptr, mkr, 2};
    B.stats = stats; B.g = g3; B.be = be3; B.bias = b3; B.dodrop = 1;
    k_bn2<<<dim3(3072, 1, 2), 256, 0, stream>>>(B);
  }
  // ---- head ----
  k_head<<<512, 256, 0, stream>>>(B3, w4, b4, outo, logp);
}

// Round 7
// 559.702 us; speedup vs baseline: 3.1955x; 1.0078x over previous
//
#include <hip/hip_runtime.h>

// Binarized MLP forward (512x784 -> 3x6144 -> 10), dual binary/real paths.
// Round 7: balanced mixed GEMM dispatch (6 equal 24-step jobs: i8 splitK2 +
// f16 splitK4, 1152 blocks all-resident); layer-1 digit GEMM merged into the
// mix dispatch (K padded to 896, float outputs exact); prep kernels fused.
//
// Precision plan (validated r1-r6):
//  - layer1 binary: exact i8-digit MFMA (4 base-256 planes of rint(x*2^24)),
//    fp64 recombination, hi/lo fp32 storage
//  - layer2/3 binary: i8 MFMA K=64, EXACT (i32 sums <= 6144, fp32-exact)
//  - real path: fp16 MFMA (error ~1e-3 << 2% thresholds)
//  - all batch-norm stats and normalization in fp64

typedef _Float16 f16x8 __attribute__((ext_vector_type(8)));
typedef _Float16 f16x4 __attribute__((ext_vector_type(4)));
typedef float f32x4 __attribute__((ext_vector_type(4)));
typedef int i32x4 __attribute__((ext_vector_type(4)));

#define MFMA16(a, b, c) __builtin_amdgcn_mfma_f32_16x16x32_f16((a), (b), (c), 0, 0, 0)
#define MFMAI8K64(a, b, c) __builtin_amdgcn_mfma_i32_16x16x64_i8((a), (b), (c), 0, 0, 0)

#define HIDC 6144
#define BATCH 512

// ---- workspace layout (bytes) ----
#define OFF_XH    0ull          // 512x832 fp16                    851,968
#define OFF_Z1LO  851968ull     // 512x6144 fp32                12,582,912
#define OFF_SB8   13434880ull   // 512x6144 i8 sign acts         3,145,728
#define OFF_RF    16580608ull   // 512x6144 fp16 real acts       6,291,456
#define OFF_STATS 22872064ull   // 4x6144 fp64                     196,608
#define OFF_PPART 23068672ull   // 2x8x2x6144 fp64               1,572,864
#define OFF_ZPB   24641536ull   // 512x6144 fp32 partial/D0     12,582,912
#define OFF_ZPR   37224448ull   // 512x6144 fp32 partial/D1     12,582,912
#define OFF_ZPR2  49807360ull   // 512x6144 fp32 partial/D2     12,582,912
#define OFF_ZPR3  62390272ull   // 512x6144 fp32 partial/D3     12,582,912
#define OFF_W1V   74973184ull   // 6144x832 fp16                10,223,616
#define OFF_WV    85196800ull   // 6144x6144 fp16               75,497,472
#define OFF_WS8   160694272ull  // 6144x6144 i8 sign weights    37,748,736
#define WS_NEED   198443008ull

// layer-1 digit planes: [512][896] i8 each, in WS8 region (free during L1)
#define A8_STRIDE 458752ull

// ---------------------------------------------------------------------------
__device__ __forceinline__ void load_lds16(const void* g, char* lds) {
  __builtin_amdgcn_global_load_lds((const __attribute__((address_space(1))) void*)g,
                                   (__attribute__((address_space(3))) void*)lds, 16, 0, 0);
}

// ---------------------------------------------------------------------------
// x-side prep: xh (512x832 fp16) + 4 digit planes (512x896 i8) of rint(x*2^24)
__global__ __launch_bounds__(256) void k_prep_xq(const float* __restrict__ x,
                                                 char* __restrict__ a8,
                                                 _Float16* __restrict__ xh) {
  int idx = blockIdx.x * 256 + threadIdx.x;  // 512*896
  if (idx >= 512 * 896) return;
  int row = idx / 896, k = idx - row * 896;
  float v = (k < 784) ? x[(size_t)row * 784 + k] : 0.f;
  int q = (int)lrintf(v * 16777216.0f);
  int d0 = ((q + 128) & 255) - 128; q = (q - d0) >> 8;
  int d1 = ((q + 128) & 255) - 128; q = (q - d1) >> 8;
  int d2 = ((q + 128) & 255) - 128; q = (q - d2) >> 8;
  a8[idx] = (char)d0;
  a8[A8_STRIDE + idx] = (char)d1;
  a8[2 * A8_STRIDE + idx] = (char)d2;
  a8[3 * A8_STRIDE + idx] = (char)q;  // |q| <= 9
  if (k < 832) xh[(size_t)row * 832 + k] = (_Float16)v;
}

// ---------------------------------------------------------------------------
// w1-side prep: s1 (6144x896 i8 sign) + w1v (6144x832 fp16)
__global__ __launch_bounds__(256) void k_prep_w1(const float* __restrict__ w,
                                                 char* __restrict__ s1,
                                                 _Float16* __restrict__ w1v) {
  int idx = blockIdx.x * 256 + threadIdx.x;  // 6144*896
  if (idx >= 6144 * 896) return;
  int r = idx / 896, k = idx - r * 896;
  float v = (k < 784) ? w[(size_t)r * 784 + k] : 0.f;
  s1[idx] = v > 0.f ? 1 : (v < 0.f ? -1 : 0);
  if (k < 832) w1v[(size_t)r * 832 + k] = (_Float16)v;
}

// ---------------------------------------------------------------------------
// w (6144x6144 fp32) -> Wv (fp16 value), Ws8 (i8 sign)
__global__ __launch_bounds__(256) void k_conv_w23(const float* __restrict__ w,
                                                  _Float16* __restrict__ wv,
                                                  char* __restrict__ ws8) {
  int idx = blockIdx.x * 256 + threadIdx.x;  // 6144*768 groups of 8
  size_t o8 = (size_t)idx * 8;
  const float* s = w + o8;
  float4 v0 = *(const float4*)s;
  float4 v1 = *(const float4*)(s + 4);
  float a[8] = {v0.x, v0.y, v0.z, v0.w, v1.x, v1.y, v1.z, v1.w};
  f16x8 hv;
  unsigned long long sbits = 0;
#pragma unroll
  for (int e = 0; e < 8; ++e) {
    hv[e] = (_Float16)a[e];
    char sg = a[e] > 0.f ? 1 : (a[e] < 0.f ? -1 : 0);
    sbits |= ((unsigned long long)(unsigned char)sg) << (8 * e);
  }
  *(f16x8*)(wv + o8) = hv;
  *(unsigned long long*)(ws8 + o8) = sbits;
}

// ---------------------------------------------------------------------------
// Mixed GEMM dispatch (up to 6 jobs via blockIdx.z):
//   is8=1: BK=128 i8 path: C = A8[512xK] @ B8[*xK]^T  (i32 accum, fp32-exact)
//   is8=0: BK=64 f16 path: C = A[512xK] @ B[*xK]^T
// BM=BN=128, 4 waves (2x2), global_load_lds, m97 2-barrier loop.
struct MixJob {
  const void* A;
  const void* B;
  float* C;
  int K;
  int kstart;
  int ksteps;
  int is8;
};
struct Mix6 { MixJob j[6]; };

__global__ __launch_bounds__(256) void k_gemm_mix(Mix6 P) {
  __shared__ __align__(16) char smem[32768];  // A @0 (16K), B @16384 (16K)
  MixJob J = P.j[0];
  if (blockIdx.z == 1) J = P.j[1];
  if (blockIdx.z == 2) J = P.j[2];
  if (blockIdx.z == 3) J = P.j[3];
  if (blockIdx.z == 4) J = P.j[4];
  if (blockIdx.z == 5) J = P.j[5];
  const int t = threadIdx.x;
  const int lane = t & 63, wid = t >> 6;
  const int wm = wid >> 1, wn = wid & 1;
  const int bn = blockIdx.x, bm = blockIdx.y;
  const size_t K = (size_t)J.K;

  if (J.is8) {
    // ---------------- i8 path (BK=128) ----------------
    const char* A = (const char*)J.A;
    const char* B = (const char*)J.B;
    i32x4 acc[4][4];
#pragma unroll
    for (int mf = 0; mf < 4; ++mf)
#pragma unroll
      for (int nf = 0; nf < 4; ++nf) acc[mf][nf] = (i32x4){0, 0, 0, 0};

    for (int kt = 0; kt < J.ksteps; ++kt) {
      const int k0 = J.kstart + kt * 128;
#pragma unroll
      for (int i = 0; i < 4; ++i) {
        int p = i * 256 + t;
        int r = p >> 3, c16 = p & 7;
        load_lds16(A + (size_t)(bm * 128 + r) * K + k0 + c16 * 16, smem + p * 16);
      }
#pragma unroll
      for (int i = 0; i < 4; ++i) {
        int p = i * 256 + t;
        int r = p >> 3, c16 = p & 7;
        load_lds16(B + (size_t)(bn * 128 + r) * K + k0 + c16 * 16, smem + 16384 + p * 16);
      }
      __syncthreads();
#pragma unroll
      for (int kk = 0; kk < 2; ++kk) {  // two K=64 halves of BK=128
        i32x4 av[4], bv[4];
#pragma unroll
        for (int mf = 0; mf < 4; ++mf) {
          int r = wm * 64 + mf * 16 + (lane & 15);
          av[mf] = *(const i32x4*)(smem + r * 128 + kk * 64 + (lane >> 4) * 16);
        }
#pragma unroll
        for (int nf = 0; nf < 4; ++nf) {
          int r = wn * 64 + nf * 16 + (lane & 15);
          bv[nf] = *(const i32x4*)(smem + 16384 + r * 128 + kk * 64 + (lane >> 4) * 16);
        }
#pragma unroll
        for (int mf = 0; mf < 4; ++mf)
#pragma unroll
          for (int nf = 0; nf < 4; ++nf) acc[mf][nf] = MFMAI8K64(av[mf], bv[nf], acc[mf][nf]);
      }
      __syncthreads();
    }
#pragma unroll
    for (int mf = 0; mf < 4; ++mf)
#pragma unroll
      for (int nf = 0; nf < 4; ++nf) {
        int col = bn * 128 + wn * 64 + nf * 16 + (lane & 15);
        int row0 = bm * 128 + wm * 64 + mf * 16 + ((lane >> 4) << 2);
#pragma unroll
        for (int rr = 0; rr < 4; ++rr) {
          J.C[(size_t)(row0 + rr) * HIDC + col] = (float)acc[mf][nf][rr];  // exact (<2^24)
        }
      }
  } else {
    // ---------------- f16 path (BK=64) ----------------
    const _Float16* A = (const _Float16*)J.A;
    const _Float16* B = (const _Float16*)J.B;
    f32x4 acc[4][4];
#pragma unroll
    for (int mf = 0; mf < 4; ++mf)
#pragma unroll
      for (int nf = 0; nf < 4; ++nf) acc[mf][nf] = (f32x4){0.f, 0.f, 0.f, 0.f};

    for (int kt = 0; kt < J.ksteps; ++kt) {
      const int k0 = J.kstart + kt * 64;
#pragma unroll
      for (int i = 0; i < 4; ++i) {
        int p = i * 256 + t;
        int r = p >> 3, c16 = p & 7;
        load_lds16(A + (size_t)(bm * 128 + r) * K + k0 + c16 * 8, smem + p * 16);
      }
#pragma unroll
      for (int i = 0; i < 4; ++i) {
        int p = i * 256 + t;
        int r = p >> 3, c16 = p & 7;
        load_lds16(B + (size_t)(bn * 128 + r) * K + k0 + c16 * 8, smem + 16384 + p * 16);
      }
      __syncthreads();
#pragma unroll
      for (int kk = 0; kk < 2; ++kk) {
        f16x8 av[4], bv[4];
#pragma unroll
        for (int mf = 0; mf < 4; ++mf) {
          int r = wm * 64 + mf * 16 + (lane & 15);
          av[mf] = *(const f16x8*)(smem + r * 128 + kk * 64 + (lane >> 4) * 16);
        }
#pragma unroll
        for (int nf = 0; nf < 4; ++nf) {
          int r = wn * 64 + nf * 16 + (lane & 15);
          bv[nf] = *(const f16x8*)(smem + 16384 + r * 128 + kk * 64 + (lane >> 4) * 16);
        }
#pragma unroll
        for (int mf = 0; mf < 4; ++mf)
#pragma unroll
          for (int nf = 0; nf < 4; ++nf) acc[mf][nf] = MFMA16(av[mf], bv[nf], acc[mf][nf]);
      }
      __syncthreads();
    }
#pragma unroll
    for (int mf = 0; mf < 4; ++mf)
#pragma unroll
      for (int nf = 0; nf < 4; ++nf) {
        int col = bn * 128 + wn * 64 + nf * 16 + (lane & 15);
        int row0 = bm * 128 + wm * 64 + mf * 16 + ((lane >> 4) << 2);
#pragma unroll
        for (int rr = 0; rr < 4; ++rr) {
          J.C[(size_t)(row0 + rr) * HIDC + col] = acc[mf][nf][rr];
        }
      }
  }
}

// ---------------------------------------------------------------------------
// Combine digit GEMMs: Z = (((D3*256+D2)*256+D1)*256+D0) * 2^-24, hi/lo fp32.
// D planes are float but hold exact integers (|.| <= 100352 < 2^24).
__global__ __launch_bounds__(256) void k_combine1(const float* __restrict__ D0,
                                                  const float* __restrict__ D1,
                                                  const float* __restrict__ D2,
                                                  const float* __restrict__ D3,
                                                  float* __restrict__ Zhi,
                                                  float* __restrict__ Zlo) {
  size_t i4 = ((size_t)blockIdx.x * 256 + threadIdx.x) * 4;  // 512*6144 elems
  float4 v0 = *(const float4*)(D0 + i4);
  float4 v1 = *(const float4*)(D1 + i4);
  float4 v2 = *(const float4*)(D2 + i4);
  float4 v3 = *(const float4*)(D3 + i4);
  const float* p0 = &v0.x;
  const float* p1 = &v1.x;
  const float* p2 = &v2.x;
  const float* p3 = &v3.x;
  float4 hi, lo;
  float* hp = &hi.x;
  float* lp = &lo.x;
#pragma unroll
  for (int e = 0; e < 4; ++e) {
    double zv = (((double)p3[e] * 256.0 + (double)p2[e]) * 256.0 + (double)p1[e]) * 256.0 +
                (double)p0[e];
    zv *= (1.0 / 16777216.0);
    float h = (float)zv;
    hp[e] = h;
    lp[e] = (float)(zv - (double)h);
  }
  *(float4*)(Zhi + i4) = hi;
  *(float4*)(Zlo + i4) = lo;
}

// ---------------------------------------------------------------------------
// Two-stage per-column stats (mean, rstd over 512 rows), fp64. Up to 3
// partial buffers per path (split-K reduction folded in here).
struct StJob { const float* Z; const float* Zp0; const float* Zp1; const float* Zp2;
               const float* msk; };
struct St2 { StJob j[2]; const float* bias; int dodrop; double* ppart; };

__global__ __launch_bounds__(256) void k_stats_part(St2 P) {
  __shared__ double sm[4][64];
  __shared__ double sq[4][64];
  const int z = blockIdx.z;
  StJob J = z ? P.j[1] : P.j[0];
  const int li = threadIdx.x & 63, rg = threadIdx.x >> 6;
  const int col = blockIdx.x * 64 + li;
  const double bb = P.dodrop ? (double)P.bias[col] : 0.0;
  double s = 0.0, s2 = 0.0;
#pragma unroll 4
  for (int rr = 0; rr < 16; ++rr) {
    int r = blockIdx.y * 64 + rg * 16 + rr;
    size_t i = (size_t)r * HIDC + col;
    double v = (double)J.Z[i];
    if (J.Zp0) v += (double)J.Zp0[i];
    if (J.Zp1) v += (double)J.Zp1[i];
    if (J.Zp2) v += (double)J.Zp2[i];
    if (P.dodrop) v = (J.msk[i] >= 0.5f) ? 2.0 * (v + bb) : 0.0;
    s += v;
    s2 += v * v;
  }
  sm[rg][li] = s;
  sq[rg][li] = s2;
  __syncthreads();
  if (rg == 0) {
    double S = sm[0][li] + sm[1][li] + sm[2][li] + sm[3][li];
    double S2 = sq[0][li] + sq[1][li] + sq[2][li] + sq[3][li];
    size_t o = ((size_t)(z * 8 + blockIdx.y) * 2) * HIDC + col;
    P.ppart[o] = S;
    P.ppart[o + HIDC] = S2;
  }
}

__global__ __launch_bounds__(256) void k_stats_fin(const double* __restrict__ ppart,
                                                   double* __restrict__ stats) {
  const int z = blockIdx.z;
  const int c = blockIdx.x * 256 + threadIdx.x;
  double S = 0.0, S2 = 0.0;
#pragma unroll
  for (int y = 0; y < 8; ++y) {
    size_t o = ((size_t)(z * 8 + y) * 2) * HIDC + c;
    S += ppart[o];
    S2 += ppart[o + HIDC];
  }
  double m = S / 512.0;
  double var = S2 / 512.0 - m * m;
  stats[z * 2 * HIDC + c] = m;
  stats[z * 2 * HIDC + HIDC + c] = 1.0 / sqrt(var + 1e-5);
}

// ---------------------------------------------------------------------------
// BN (+optional dropout) + hardtanh, fp64 math; dual-path via grid.z.
// auxmode: 0 -> aux (i8) = sign(out) ; 1 -> aux (f16) = out ; 2 -> none.
struct BnJob { float* Z; const float* Zp0; const float* Zp1; const float* Zp2;
               void* aux; const float* msk; int auxmode; };
struct Bn2 {
  BnJob j[2];
  const double* stats;
  const float* g; const float* be; const float* bias;
  int dodrop;
};

__global__ __launch_bounds__(256) void k_bn2(Bn2 P) {
  const int z = blockIdx.z;
  BnJob J = z ? P.j[1] : P.j[0];
  const double* m_arr = P.stats + (size_t)z * 2 * HIDC;
  const double* r_arr = m_arr + HIDC;
  int idx = blockIdx.x * 256 + threadIdx.x;  // 512*1536 float4 positions
  int row = idx / 1536;
  int c4 = (idx - row * 1536) * 4;
  size_t base = (size_t)row * HIDC + c4;
  float4 zv = *(const float4*)(J.Z + base);
  float zz[4] = {zv.x, zv.y, zv.z, zv.w};
  double ex[4] = {0.0, 0.0, 0.0, 0.0};
  if (J.Zp0) {
    float4 t4 = *(const float4*)(J.Zp0 + base);
    ex[0] += t4.x; ex[1] += t4.y; ex[2] += t4.z; ex[3] += t4.w;
  }
  if (J.Zp1) {
    float4 t4 = *(const float4*)(J.Zp1 + base);
    ex[0] += t4.x; ex[1] += t4.y; ex[2] += t4.z; ex[3] += t4.w;
  }
  if (J.Zp2) {
    float4 t4 = *(const float4*)(J.Zp2 + base);
    ex[0] += t4.x; ex[1] += t4.y; ex[2] += t4.z; ex[3] += t4.w;
  }
  float mk[4] = {1.f, 1.f, 1.f, 1.f};
  if (P.dodrop) {
    float4 t4 = *(const float4*)(J.msk + base);
    mk[0] = t4.x; mk[1] = t4.y; mk[2] = t4.z; mk[3] = t4.w;
  }
  float o[4];
  f16x4 a4;
  int sbits = 0;
#pragma unroll
  for (int e = 0; e < 4; ++e) {
    int c = c4 + e;
    double v = (double)zz[e] + ex[e];
    if (P.dodrop) v = (mk[e] >= 0.5f) ? 2.0 * (v + (double)P.bias[c]) : 0.0;
    double bnv = (double)P.g[c] * ((v - m_arr[c]) * r_arr[c]) + (double)P.be[c];
    bnv = bnv > 1.0 ? 1.0 : (bnv < -1.0 ? -1.0 : bnv);
    o[e] = (float)bnv;
    char sg = bnv > 0.0 ? 1 : (bnv < 0.0 ? -1 : 0);
    sbits |= ((int)(unsigned char)sg) << (8 * e);
    a4[e] = (_Float16)o[e];
  }
  float4 ov = {o[0], o[1], o[2], o[3]};
  *(float4*)(J.Z + base) = ov;
  if (J.auxmode == 0) *(int*)((char*)J.aux + base) = sbits;
  if (J.auxmode == 1) *(f16x4*)((_Float16*)J.aux + base) = a4;
}

// ---------------------------------------------------------------------------
// Head: out = Bout3 @ w4^T + b4 (512x10, K=6144) + log_softmax, one block/row.
__global__ __launch_bounds__(256) void k_head(const float* __restrict__ B3,
                                              const float* __restrict__ w4,
                                              const float* __restrict__ b4,
                                              float* __restrict__ out,
                                              float* __restrict__ logp) {
  const int row = blockIdx.x, t = threadIdx.x;
  float acc[10];
#pragma unroll
  for (int j = 0; j < 10; ++j) acc[j] = 0.f;
  const float* a = B3 + (size_t)row * HIDC;
  for (int k4 = t; k4 < 1536; k4 += 256) {
    float4 av = *(const float4*)(a + k4 * 4);
#pragma unroll
    for (int j = 0; j < 10; ++j) {
      float4 wv = *(const float4*)(w4 + (size_t)j * HIDC + k4 * 4);
      acc[j] += av.x * wv.x + av.y * wv.y + av.z * wv.z + av.w * wv.w;
    }
  }
#pragma unroll
  for (int j = 0; j < 10; ++j)
    for (int off = 32; off; off >>= 1) acc[j] += __shfl_down(acc[j], off);
  __shared__ float sred[4][10];
  int wid = t >> 6, ln = t & 63;
  if (ln == 0)
#pragma unroll
    for (int j = 0; j < 10; ++j) sred[wid][j] = acc[j];
  __syncthreads();
  if (t == 0) {
    double o[10];
    double mx = -1e300;
#pragma unroll
    for (int j = 0; j < 10; ++j) {
      o[j] = (double)sred[0][j] + sred[1][j] + sred[2][j] + sred[3][j] + (double)b4[j];
      mx = o[j] > mx ? o[j] : mx;
    }
    double s = 0.0;
#pragma unroll
    for (int j = 0; j < 10; ++j) s += exp(o[j] - mx);
    double l = log(s) + mx;
#pragma unroll
    for (int j = 0; j < 10; ++j) {
      out[row * 10 + j] = (float)o[j];
      logp[row * 10 + j] = (float)(o[j] - l);
    }
  }
}

// ===========================================================================
extern "C" void kernel_launch(void* const* d_in, const int* in_sizes, int n_in,
                              void* d_out, int out_size, void* d_ws, size_t ws_size,
                              hipStream_t stream) {
  const float* x   = (const float*)d_in[0];
  const float* mkb = (const float*)d_in[1];
  const float* mkr = (const float*)d_in[2];
  const float* w1  = (const float*)d_in[3];
  const float* w2  = (const float*)d_in[5];
  const float* w3  = (const float*)d_in[7];
  const float* b3  = (const float*)d_in[8];
  const float* w4  = (const float*)d_in[9];
  const float* b4  = (const float*)d_in[10];
  const float* g1  = (const float*)d_in[11]; const float* be1 = (const float*)d_in[12];
  const float* g2  = (const float*)d_in[13]; const float* be2 = (const float*)d_in[14];
  const float* g3  = (const float*)d_in[15]; const float* be3 = (const float*)d_in[16];

  float* outp = (float*)d_out;
  float* logp = outp;
  float* outo = outp + 5120;
  float* B1 = outp + 10240;
  float* R1 = outp + 3155968;
  float* B2 = outp + 6301696;
  float* R2 = outp + 9447424;
  float* B3 = outp + 12593152;
  float* R3 = outp + 15738880;

  char* ws = (char*)d_ws;
  _Float16* xh  = (_Float16*)(ws + OFF_XH);
  float* z1lo   = (float*)(ws + OFF_Z1LO);
  char* sB8     = (char*)(ws + OFF_SB8);
  _Float16* rF  = (_Float16*)(ws + OFF_RF);
  double* stats = (double*)(ws + OFF_STATS);
  double* ppart = (double*)(ws + OFF_PPART);
  float* zpb    = (float*)(ws + OFF_ZPB);
  float* zpr    = (float*)(ws + OFF_ZPR);
  float* zpr2   = (float*)(ws + OFF_ZPR2);
  float* zpr3   = (float*)(ws + OFF_ZPR3);
  _Float16* w1v = (_Float16*)(ws + OFF_W1V);
  _Float16* wv  = (_Float16*)(ws + OFF_WV);
  char* ws8     = (char*)(ws + OFF_WS8);
  // layer-1-phase aliases (WS8 region free until layer 2; D planes = partial bufs)
  char* a8 = (char*)(ws + OFF_WS8);                 // 4 digit planes (1.8 MB)
  char* s1 = (char*)(ws + OFF_WS8 + 4ull * A8_STRIDE);  // sign(w1) i8 (5.5 MB)

  // ---- layer 1 prep ----
  k_prep_xq<<<1792, 256, 0, stream>>>(x, a8, xh);
  k_prep_w1<<<21504, 256, 0, stream>>>(w1, s1, w1v);
  // ---- layer 1 GEMMs: 4 digit i8 jobs (K=896, 7 steps) + real f16 (13 steps) ----
  {
    Mix6 P{};
    P.j[0] = {a8,                 s1, zpb,  896, 0, 7, 1};
    P.j[1] = {a8 + A8_STRIDE,     s1, zpr,  896, 0, 7, 1};
    P.j[2] = {a8 + 2 * A8_STRIDE, s1, zpr2, 896, 0, 7, 1};
    P.j[3] = {a8 + 3 * A8_STRIDE, s1, zpr3, 896, 0, 7, 1};
    P.j[4] = {xh, w1v, R1, 832, 0, 13, 0};
    P.j[5] = P.j[4];
    k_gemm_mix<<<dim3(48, 4, 5), 256, 0, stream>>>(P);
  }
  k_combine1<<<3072, 256, 0, stream>>>(zpb, zpr, zpr2, zpr3, B1, z1lo);
  {
    St2 S{};
    S.j[0] = {B1, z1lo, nullptr, nullptr, nullptr};
    S.j[1] = {R1, nullptr, nullptr, nullptr, nullptr};
    S.bias = nullptr; S.dodrop = 0; S.ppart = ppart;
    k_stats_part<<<dim3(96, 8, 2), 256, 0, stream>>>(S);
    k_stats_fin<<<dim3(24, 1, 2), 256, 0, stream>>>(ppart, stats);
    Bn2 B{};
    B.j[0] = {B1, z1lo, nullptr, nullptr, sB8, nullptr, 0};
    B.j[1] = {R1, nullptr, nullptr, nullptr, rF, nullptr, 1};
    B.stats = stats; B.g = g1; B.be = be1; B.bias = nullptr; B.dodrop = 0;
    k_bn2<<<dim3(3072, 1, 2), 256, 0, stream>>>(B);
  }
  // ---- layer 2 ----
  k_conv_w23<<<18432, 256, 0, stream>>>(w2, wv, ws8);
  {
    Mix6 P{};
    P.j[0] = {sB8, ws8, B2,   HIDC, 0,    24, 1};
    P.j[1] = {sB8, ws8, zpb,  HIDC, 3072, 24, 1};
    P.j[2] = {rF,  wv,  R2,   HIDC, 0,    24, 0};
    P.j[3] = {rF,  wv,  zpr,  HIDC, 1536, 24, 0};
    P.j[4] = {rF,  wv,  zpr2, HIDC, 3072, 24, 0};
    P.j[5] = {rF,  wv,  zpr3, HIDC, 4608, 24, 0};
    k_gemm_mix<<<dim3(48, 4, 6), 256, 0, stream>>>(P);
  }
  {
    St2 S{};
    S.j[0] = {B2, zpb, nullptr, nullptr, nullptr};
    S.j[1] = {R2, zpr, zpr2, zpr3, nullptr};
    S.bias = nullptr; S.dodrop = 0; S.ppart = ppart;
    k_stats_part<<<dim3(96, 8, 2), 256, 0, stream>>>(S);
    k_stats_fin<<<dim3(24, 1, 2), 256, 0, stream>>>(ppart, stats);
    Bn2 B{};
    B.j[0] = {B2, zpb, nullptr, nullptr, sB8, nullptr, 0};
    B.j[1] = {R2, zpr, zpr2, zpr3, rF, nullptr, 1};
    B.stats = stats; B.g = g2; B.be = be2; B.bias = nullptr; B.dodrop = 0;
    k_bn2<<<dim3(3072, 1, 2), 256, 0, stream>>>(B);
  }
  // ---- layer 3 ----
  k_conv_w23<<<18432, 256, 0, stream>>>(w3, wv, ws8);
  {
    Mix6 P{};
    P.j[0] = {sB8, ws8, B3,   HIDC, 0,    24, 1};
    P.j[1] = {sB8, ws8, zpb,  HIDC, 3072, 24, 1};
    P.j[2] = {rF,  wv,  R3,   HIDC, 0,    24, 0};
    P.j[3] = {rF,  wv,  zpr,  HIDC, 1536, 24, 0};
    P.j[4] = {rF,  wv,  zpr2, HIDC, 3072, 24, 0};
    P.j[5] = {rF,  wv,  zpr3, HIDC, 4608, 24, 0};
    k_gemm_mix<<<dim3(48, 4, 6), 256, 0, stream>>>(P);
  }
  {
    St2 S{};
    S.j[0] = {B3, zpb, nullptr, nullptr, mkb};
    S.j[1] = {R3, zpr, zpr2, zpr3, mkr};
    S.bias = b3; S.dodrop = 1; S.ppart = ppart;
    k_stats_part<<<dim3(96, 8, 2), 256, 0, stream>>>(S);
    k_stats_fin<<<dim3(24, 1, 2), 256, 0, stream>>>(ppart, stats);
    Bn2 B{};
    B.j[0] = {B3, zpb, nullptr, nullptr, nullptr, mkb, 2};
    B.j[1] = {R3, zpr, zpr2, zpr3, nullptr, mkr, 2};
    B.stats = stats; B.g = g3; B.be = be3; B.bias = b3; B.dodrop = 1;
    k_bn2<<<dim3(3072, 1, 2), 256, 0, stream>>>(B);
  }
  // ---- head ----
  k_head<<<512, 256, 0, stream>>>(B3, w4, b4, outo, logp);
}